// Round 6
// baseline (1011.503 us; speedup 1.0000x reference)
//
#include <hip/hip_runtime.h>
#include <math.h>

// Problem constants (match reference)
constexpr int NN   = 50000;    // nodes
constexpr int EE   = 1000000;  // edges (before self loops)
constexpr int E2   = EE + NN;  // edges incl self loops
constexpr int HEADS = 4;
constexpr int HID  = 64;
constexpr int GG   = 64;       // graphs
constexpr int NCLS = 2;
constexpr float NEG = 0.2f;

__device__ __forceinline__ float leaky(float v){ return v > 0.f ? v : NEG * v; }

// ---------------------------------------------------------------- CSR build
__global__ __launch_bounds__(256) void k_edge_count(const int* __restrict__ dst,
                                                    const float* __restrict__ ea,
                                                    int* __restrict__ deg,
                                                    float* __restrict__ easum){
  int e = blockIdx.x * 256 + threadIdx.x;
  if (e >= EE) return;
  int d = dst[e];
  atomicAdd(&deg[d], 1);
  atomicAdd(&easum[d*2+0], ea[e*2+0]);
  atomicAdd(&easum[d*2+1], ea[e*2+1]);
}

__global__ __launch_bounds__(1024) void k_scan1(const int* __restrict__ deg,
                                                int* __restrict__ tmp,
                                                int* __restrict__ bsum){
  __shared__ int s[1024];
  int t = threadIdx.x;
  int gid = blockIdx.x * 1024 + t;
  int v = (gid < NN) ? (deg[gid] + 1) : 0;   // +1 for self loop
  s[t] = v;
  __syncthreads();
  for (int off = 1; off < 1024; off <<= 1){
    int u = (t >= off) ? s[t - off] : 0;
    __syncthreads();
    s[t] += u;
    __syncthreads();
  }
  if (gid < NN) tmp[gid] = s[t];             // inclusive scan
  if (t == 1023) bsum[blockIdx.x] = s[1023];
}

__global__ void k_scan2(int* bsum, int nb){
  if (threadIdx.x == 0 && blockIdx.x == 0){
    int run = 0;
    for (int b = 0; b < nb; ++b){ int x = bsum[b]; bsum[b] = run; run += x; }
  }
}

__global__ __launch_bounds__(256) void k_scan3(const int* __restrict__ tmp,
                                               const int* __restrict__ bsum,
                                               const int* __restrict__ deg,
                                               const float* __restrict__ easum,
                                               int* __restrict__ offsets,
                                               int* __restrict__ cursor,
                                               float* __restrict__ meanattr){
  int i = blockIdx.x * 256 + threadIdx.x;
  if (i >= NN) return;
  int d = deg[i];
  int excl = tmp[i] - (d + 1) + bsum[i >> 10];
  offsets[i] = excl;
  cursor[i]  = excl;
  float c = fmaxf((float)d, 1.0f);           // fill_value='mean' semantics
  meanattr[i*2+0] = easum[i*2+0] / c;
  meanattr[i*2+1] = easum[i*2+1] / c;
}

__global__ __launch_bounds__(256) void k_fill(const int* __restrict__ dst,
                                              int* __restrict__ cursor,
                                              int* __restrict__ eid){
  int t = blockIdx.x * 256 + threadIdx.x;
  if (t < EE){
    int d = dst[t];
    int p = atomicAdd(&cursor[d], 1);
    eid[p] = t;
  } else if (t < E2){
    int i = t - EE;                          // self loop edge id = EE + i
    int p = atomicAdd(&cursor[i], 1);
    eid[p] = EE + i;
  }
}

// Fold edge-attr projection+attention into a [heads][2] vector:
// a_edge[e][h] = ea[e,0]*ve[h][0] + ea[e,1]*ve[h][1]
__global__ void k_ve(const float* __restrict__ We1, const float* __restrict__ a1e,
                     const float* __restrict__ We2, const float* __restrict__ a2e,
                     float* __restrict__ ve){
  int t = threadIdx.x;
  if (t < 8){
    int h = t >> 1, d = t & 1;
    float s = 0.f;
    for (int c = 0; c < HID; ++c) s += We1[d*256 + h*64 + c] * a1e[h*64 + c];
    ve[t] = s;                               // ve[h*2+d]
  } else if (t < 10){
    int d = t - 8;
    float s = 0.f;
    for (int c = 0; c < HID; ++c) s += We2[d*64 + c] * a2e[c];
    ve[8 + d] = s;                           // ve2[d]
  }
}

// ------------------------------------------------------- layer 1 projection
// h1 = x @ W1  ([N,64]@[64,256]).
// Block = 256 threads = 8 rows; thread t owns output col t for all 8 rows.
// W1 columns read per-k coalesced from L1/L2 (W1 = 64 KB, CU-resident).
// x rows staged in 2 KB LDS, read as broadcast ds_read_b128.
// 8 rows x 4 k-partials = 32 independent FMA chains of depth 16; ~50 VGPR.
constexpr int PR1 = 8;
__global__ __launch_bounds__(256) void k_proj1(const float* __restrict__ x,
                                               const float* __restrict__ W1,
                                               const float* __restrict__ a1s,
                                               const float* __restrict__ a1d,
                                               float* __restrict__ h1,
                                               float* __restrict__ asrc,
                                               float* __restrict__ adst){
  __shared__ float xs[PR1][64];
  int t = threadIdx.x;
  int row0 = blockIdx.x * PR1;               // NN % PR1 == 0
  for (int i = t; i < PR1*64; i += 256)
    xs[i >> 6][i & 63] = x[row0*64 + i];
  __syncthreads();
  float acc[PR1][4] = {};
  #pragma unroll
  for (int k4 = 0; k4 < 16; ++k4){
    float wv0 = W1[(k4*4+0)*256 + t];
    float wv1 = W1[(k4*4+1)*256 + t];
    float wv2 = W1[(k4*4+2)*256 + t];
    float wv3 = W1[(k4*4+3)*256 + t];
    #pragma unroll
    for (int r = 0; r < PR1; ++r){
      float4 xq = *(const float4*)&xs[r][k4*4];
      acc[r][0] = fmaf(xq.x, wv0, acc[r][0]);
      acc[r][1] = fmaf(xq.y, wv1, acc[r][1]);
      acc[r][2] = fmaf(xq.z, wv2, acc[r][2]);
      acc[r][3] = fmaf(xq.w, wv3, acc[r][3]);
    }
  }
  int lane = t & 63, wave = t >> 6;          // wave == head
  float as_w = a1s[t], ad_w = a1d[t];        // a1s flat [4*64]; col == flat idx
  #pragma unroll
  for (int r = 0; r < PR1; ++r){
    int row = row0 + r;
    float hv = (acc[r][0] + acc[r][1]) + (acc[r][2] + acc[r][3]);
    h1[row*256 + t] = hv;
    float ps = hv * as_w, pd = hv * ad_w;
    #pragma unroll
    for (int off = 32; off; off >>= 1){ ps += __shfl_xor(ps, off); pd += __shfl_xor(pd, off); }
    if (lane == 0){ asrc[row*4 + wave] = ps; adst[row*4 + wave] = pd; }
  }
}

// ----------------------------------------------- layer 1 softmax + aggregate
// One wave per node. Phase A: lane-parallel max over in-edges (logits for the
// first 64 edges cached in registers). Phase B: lane-parallel w=exp(al-mx).
// Phase C: serial gather where s/w come from __shfl register broadcast —
// no dependent global loads, no divergent branch in the hot loop.
__global__ __launch_bounds__(256) void k_agg1(const int* __restrict__ src,
                                              const float* __restrict__ ea,
                                              const float* __restrict__ meanattr,
                                              const int* __restrict__ offsets,
                                              const int* __restrict__ deg,
                                              const int* __restrict__ eid,
                                              const float* __restrict__ h1,
                                              const float* __restrict__ asrc,
                                              const float* __restrict__ adst,
                                              const float* __restrict__ ve,
                                              const float* __restrict__ b1,
                                              float* __restrict__ out1){
  int node = blockIdx.x * 4 + (threadIdx.x >> 6);
  int lane = threadIdx.x & 63;
  int lo  = offsets[node];
  int cnt = deg[node] + 1;
  int h = lane >> 4;
  float ad0 = adst[node*4+0], ad1 = adst[node*4+1];
  float ad2 = adst[node*4+2], ad3 = adst[node*4+3];
  float v00 = ve[0], v01 = ve[1], v10 = ve[2], v11 = ve[3];
  float v20 = ve[4], v21 = ve[5], v30 = ve[6], v31 = ve[7];

  // Phase A: per-head segment max, lane-parallel; cache chunk-0 logits+src
  float mx0 = -INFINITY, mx1 = -INFINITY, mx2 = -INFINITY, mx3 = -INFINITY;
  float cal0 = 0.f, cal1 = 0.f, cal2 = 0.f, cal3 = 0.f;
  int   cs = 0;
  if (lane < cnt){
    int e = eid[lo + lane];
    int s; float e0, e1;
    if (e < EE){ s = src[e]; e0 = ea[e*2]; e1 = ea[e*2+1]; }
    else       { s = node;   e0 = meanattr[node*2]; e1 = meanattr[node*2+1]; }
    float s0 = asrc[s*4+0], s1 = asrc[s*4+1], s2 = asrc[s*4+2], s3 = asrc[s*4+3];
    cal0 = leaky(s0 + ad0 + e0*v00 + e1*v01);
    cal1 = leaky(s1 + ad1 + e0*v10 + e1*v11);
    cal2 = leaky(s2 + ad2 + e0*v20 + e1*v21);
    cal3 = leaky(s3 + ad3 + e0*v30 + e1*v31);
    cs = s;
    mx0 = cal0; mx1 = cal1; mx2 = cal2; mx3 = cal3;
  }
  for (int k = lane + 64; k < cnt; k += 64){   // essentially never taken (deg~20)
    int e = eid[lo + k];
    int s; float e0, e1;
    if (e < EE){ s = src[e]; e0 = ea[e*2]; e1 = ea[e*2+1]; }
    else       { s = node;   e0 = meanattr[node*2]; e1 = meanattr[node*2+1]; }
    float s0 = asrc[s*4+0], s1 = asrc[s*4+1], s2 = asrc[s*4+2], s3 = asrc[s*4+3];
    mx0 = fmaxf(mx0, leaky(s0 + ad0 + e0*v00 + e1*v01));
    mx1 = fmaxf(mx1, leaky(s1 + ad1 + e0*v10 + e1*v11));
    mx2 = fmaxf(mx2, leaky(s2 + ad2 + e0*v20 + e1*v21));
    mx3 = fmaxf(mx3, leaky(s3 + ad3 + e0*v30 + e1*v31));
  }
  #pragma unroll
  for (int off = 32; off; off >>= 1){
    mx0 = fmaxf(mx0, __shfl_xor(mx0, off));
    mx1 = fmaxf(mx1, __shfl_xor(mx1, off));
    mx2 = fmaxf(mx2, __shfl_xor(mx2, off));
    mx3 = fmaxf(mx3, __shfl_xor(mx3, off));
  }

  // Phases B+C per 64-edge chunk
  float4 acc = make_float4(0.f, 0.f, 0.f, 0.f);
  float den = 0.f;
  for (int base = 0; base < cnt; base += 64){
    int k = base + lane;
    float w0 = 0.f, w1 = 0.f, w2 = 0.f, w3 = 0.f;
    int sv = 0;
    if (k < cnt){
      float a0, a1, a2, a3; int s;
      if (base == 0){ s = cs; a0 = cal0; a1 = cal1; a2 = cal2; a3 = cal3; }
      else {
        int e = eid[lo + k];
        float e0, e1;
        if (e < EE){ s = src[e]; e0 = ea[e*2]; e1 = ea[e*2+1]; }
        else       { s = node;   e0 = meanattr[node*2]; e1 = meanattr[node*2+1]; }
        a0 = leaky(asrc[s*4+0] + ad0 + e0*v00 + e1*v01);
        a1 = leaky(asrc[s*4+1] + ad1 + e0*v10 + e1*v11);
        a2 = leaky(asrc[s*4+2] + ad2 + e0*v20 + e1*v21);
        a3 = leaky(asrc[s*4+3] + ad3 + e0*v30 + e1*v31);
      }
      w0 = __expf(a0 - mx0); w1 = __expf(a1 - mx1);
      w2 = __expf(a2 - mx2); w3 = __expf(a3 - mx3);
      sv = s;
    }
    int m = min(64, cnt - base);
    #pragma unroll 4
    for (int k2 = 0; k2 < m; ++k2){
      int   s  = __shfl(sv, k2);
      float q0 = __shfl(w0, k2);
      float q1 = __shfl(w1, k2);
      float q2 = __shfl(w2, k2);
      float q3 = __shfl(w3, k2);
      float w  = (h == 0) ? q0 : (h == 1) ? q1 : (h == 2) ? q2 : q3;
      float4 v = *(const float4*)&h1[s*256 + lane*4];
      den += w;
      acc.x = fmaf(w, v.x, acc.x);
      acc.y = fmaf(w, v.y, acc.y);
      acc.z = fmaf(w, v.z, acc.z);
      acc.w = fmaf(w, v.w, acc.w);
    }
  }
  float4 bb = *(const float4*)&b1[lane*4];
  float inv = 1.f / den;
  float4 o;
  o.x = fmaxf(fmaf(acc.x, inv, bb.x), 0.f);
  o.y = fmaxf(fmaf(acc.y, inv, bb.y), 0.f);
  o.z = fmaxf(fmaf(acc.z, inv, bb.z), 0.f);
  o.w = fmaxf(fmaf(acc.w, inv, bb.w), 0.f);
  *(float4*)&out1[node*256 + lane*4] = o;
}

// ------------------------------------------------------- layer 2 projection
// h2 = out1 @ W2  ([N,256]@[256,64]).
// Block = 256 threads = 8 rows; wave w owns rows {2w, 2w+1}, lane = col.
// W2 read per-k coalesced from L1/L2 (64 KB, CU-resident); out1 rows staged
// in 8 KB LDS, read as broadcast ds_read_b128. 2 rows x 4 partials = 8
// independent chains of depth 64; ~40 VGPR.
constexpr int PR2 = 8;
__global__ __launch_bounds__(256) void k_proj2(const float* __restrict__ out1,
                                               const float* __restrict__ W2,
                                               const float* __restrict__ a2s,
                                               const float* __restrict__ a2d,
                                               float* __restrict__ h2,
                                               float* __restrict__ asrc,
                                               float* __restrict__ adst){
  __shared__ float xs[PR2][256];
  int t = threadIdx.x;
  int row0 = blockIdx.x * PR2;               // NN % PR2 == 0
  for (int i = t*4; i < PR2*256; i += 1024)
    *(float4*)&xs[i >> 8][i & 255] = *(const float4*)&out1[row0*256 + i];
  __syncthreads();
  int lane = t & 63, wave = t >> 6;
  int ra = wave*2, rb = wave*2 + 1;
  float accA[4] = {}, accB[4] = {};
  #pragma unroll
  for (int k4 = 0; k4 < 64; ++k4){
    float wv0 = W2[(k4*4+0)*64 + lane];
    float wv1 = W2[(k4*4+1)*64 + lane];
    float wv2 = W2[(k4*4+2)*64 + lane];
    float wv3 = W2[(k4*4+3)*64 + lane];
    float4 xa = *(const float4*)&xs[ra][k4*4];
    float4 xb = *(const float4*)&xs[rb][k4*4];
    accA[0] = fmaf(xa.x, wv0, accA[0]);
    accA[1] = fmaf(xa.y, wv1, accA[1]);
    accA[2] = fmaf(xa.z, wv2, accA[2]);
    accA[3] = fmaf(xa.w, wv3, accA[3]);
    accB[0] = fmaf(xb.x, wv0, accB[0]);
    accB[1] = fmaf(xb.y, wv1, accB[1]);
    accB[2] = fmaf(xb.z, wv2, accB[2]);
    accB[3] = fmaf(xb.w, wv3, accB[3]);
  }
  float aw_s = a2s[lane], aw_d = a2d[lane];
  #pragma unroll
  for (int r = 0; r < 2; ++r){
    int row = row0 + (r == 0 ? ra : rb);
    float hv = (r == 0) ? ((accA[0]+accA[1]) + (accA[2]+accA[3]))
                        : ((accB[0]+accB[1]) + (accB[2]+accB[3]));
    h2[row*64 + lane] = hv;
    float ps = hv * aw_s, pd = hv * aw_d;
    #pragma unroll
    for (int off = 32; off; off >>= 1){ ps += __shfl_xor(ps, off); pd += __shfl_xor(pd, off); }
    if (lane == 0){ asrc[row] = ps; adst[row] = pd; }
  }
}

// ----------------------------------------------- layer 2 softmax + aggregate
__global__ __launch_bounds__(256) void k_agg2(const int* __restrict__ src,
                                              const float* __restrict__ ea,
                                              const float* __restrict__ meanattr,
                                              const int* __restrict__ offsets,
                                              const int* __restrict__ deg,
                                              const int* __restrict__ eid,
                                              const float* __restrict__ h2,
                                              const float* __restrict__ asrc,
                                              const float* __restrict__ adst,
                                              const float* __restrict__ ve,
                                              const float* __restrict__ b2,
                                              float* __restrict__ out2){
  int node = blockIdx.x * 4 + (threadIdx.x >> 6);
  int lane = threadIdx.x & 63;
  int lo  = offsets[node];
  int cnt = deg[node] + 1;
  float adI = adst[node];
  float v0 = ve[8], v1 = ve[9];

  float mx = -INFINITY, cal = 0.f;
  int cs = 0;
  if (lane < cnt){
    int e = eid[lo + lane];
    int s; float e0, e1;
    if (e < EE){ s = src[e]; e0 = ea[e*2]; e1 = ea[e*2+1]; }
    else       { s = node;   e0 = meanattr[node*2]; e1 = meanattr[node*2+1]; }
    cal = leaky(asrc[s] + adI + e0*v0 + e1*v1);
    cs = s;
    mx = cal;
  }
  for (int k = lane + 64; k < cnt; k += 64){
    int e = eid[lo + k];
    int s; float e0, e1;
    if (e < EE){ s = src[e]; e0 = ea[e*2]; e1 = ea[e*2+1]; }
    else       { s = node;   e0 = meanattr[node*2]; e1 = meanattr[node*2+1]; }
    mx = fmaxf(mx, leaky(asrc[s] + adI + e0*v0 + e1*v1));
  }
  #pragma unroll
  for (int off = 32; off; off >>= 1) mx = fmaxf(mx, __shfl_xor(mx, off));

  float acc = 0.f, den = 0.f;
  for (int base = 0; base < cnt; base += 64){
    int k = base + lane;
    float w = 0.f; int sv = 0;
    if (k < cnt){
      float a; int s;
      if (base == 0){ s = cs; a = cal; }
      else {
        int e = eid[lo + k];
        float e0, e1;
        if (e < EE){ s = src[e]; e0 = ea[e*2]; e1 = ea[e*2+1]; }
        else       { s = node;   e0 = meanattr[node*2]; e1 = meanattr[node*2+1]; }
        a = leaky(asrc[s] + adI + e0*v0 + e1*v1);
      }
      w = __expf(a - mx);
      sv = s;
    }
    int m = min(64, cnt - base);
    #pragma unroll 4
    for (int k2 = 0; k2 < m; ++k2){
      int   s  = __shfl(sv, k2);
      float ww = __shfl(w,  k2);
      den += ww;
      acc = fmaf(ww, h2[s*64 + lane], acc);
    }
  }
  out2[node*64 + lane] = fmaxf(acc / den + b2[lane], 0.f);
}

// ------------------------------------------------------- pool + classifier
__global__ __launch_bounds__(256) void k_pool(const float* __restrict__ out2,
                                              const int* __restrict__ batch,
                                              const float* __restrict__ Wl,
                                              const float* __restrict__ bl,
                                              float* __restrict__ out){
  __shared__ float red[4][64];
  __shared__ float sh_mean[64];
  int g = blockIdx.x;
  int t = threadIdx.x, lane = t & 63, wave = t >> 6;
  // batch is sorted: binary search graph range
  int lo = 0, hi = NN;
  while (lo < hi){ int m = (lo + hi) >> 1; if (batch[m] < g) lo = m + 1; else hi = m; }
  int start = lo;
  lo = start; hi = NN;
  while (lo < hi){ int m = (lo + hi) >> 1; if (batch[m] < g + 1) lo = m + 1; else hi = m; }
  int end = lo;
  float acc = 0.f;
  for (int n = start + wave; n < end; n += 4) acc += out2[n*64 + lane];
  red[wave][lane] = acc;
  __syncthreads();
  if (wave == 0){
    float s = red[0][lane] + red[1][lane] + red[2][lane] + red[3][lane];
    sh_mean[lane] = s / fmaxf((float)(end - start), 1.0f);
  }
  __syncthreads();
  if (t < NCLS){
    float o = bl[t];
    for (int c = 0; c < HID; ++c) o = fmaf(sh_mean[c], Wl[c*NCLS + t], o);
    out[g*NCLS + t] = o;
  }
}

// ---------------------------------------------------------------- launcher
extern "C" void kernel_launch(void* const* d_in, const int* in_sizes, int n_in,
                              void* d_out, int out_size, void* d_ws, size_t ws_size,
                              hipStream_t stream){
  const float* x     = (const float*)d_in[0];
  const int*   ei    = (const int*)  d_in[1];
  const float* ea    = (const float*)d_in[2];
  const int*   batch = (const int*)  d_in[3];
  const float* W1    = (const float*)d_in[4];
  const float* a1s   = (const float*)d_in[5];
  const float* a1d   = (const float*)d_in[6];
  const float* We1   = (const float*)d_in[7];
  const float* a1e   = (const float*)d_in[8];
  const float* b1    = (const float*)d_in[9];
  const float* W2    = (const float*)d_in[10];
  const float* a2s   = (const float*)d_in[11];
  const float* a2d   = (const float*)d_in[12];
  const float* We2   = (const float*)d_in[13];
  const float* a2e   = (const float*)d_in[14];
  const float* b2    = (const float*)d_in[15];
  const float* Wl    = (const float*)d_in[16];
  const float* bl    = (const float*)d_in[17];
  const int* srcp = ei;        // edge_index[0]
  const int* dstp = ei + EE;   // edge_index[1]

  char* base = (char*)d_ws;
  size_t off = 0;
  auto alloc = [&](size_t bytes) -> char* {
    char* p = base + off;
    off = (off + bytes + 255) & ~(size_t)255;
    return p;
  };
  // Large persistent regions
  float* h1   = (float*)alloc((size_t)NN*256*4);   // 51.2 MB (layer-1 proj)
  float* out1 = (float*)alloc((size_t)NN*256*4);   // 51.2 MB (layer-1 out)
  // h2/out2 alias the h1 region: h1 is dead once k_agg1 completes, and
  // k_proj2 (writes h2) / k_agg2 (writes out2) run strictly after it.
  float* h2   = (float*)h1;                        // NN*64*4 = 12.8 MB
  float* out2 = (float*)(h1 + (size_t)NN*64);      // next 12.8 MB of h1 region
  // Small regions
  float* asrc1    = (float*)alloc((size_t)NN*4*4);
  float* adst1    = (float*)alloc((size_t)NN*4*4);
  float* asrc2    = (float*)alloc((size_t)NN*4);
  float* adst2    = (float*)alloc((size_t)NN*4);
  float* easum    = (float*)alloc((size_t)NN*2*4);
  float* meanattr = (float*)alloc((size_t)NN*2*4);
  int*   deg      = (int*)  alloc((size_t)NN*4);
  int*   offsets  = (int*)  alloc((size_t)NN*4);
  int*   cursor   = (int*)  alloc((size_t)NN*4);
  int*   eid      = (int*)  alloc((size_t)E2*4);
  int*   stmp     = (int*)  alloc((size_t)NN*4);
  int*   bsum     = (int*)  alloc(64*4);
  float* ve       = (float*)alloc(16*4);
  if (off > ws_size) return;   // workspace too small: fail loudly (poisoned out)

  hipMemsetAsync(deg,   0, (size_t)NN*4,   stream);
  hipMemsetAsync(easum, 0, (size_t)NN*2*4, stream);

  int nb = (NN + 1023) / 1024;
  k_edge_count<<<(EE + 255)/256, 256, 0, stream>>>(dstp, ea, deg, easum);
  k_scan1<<<nb, 1024, 0, stream>>>(deg, stmp, bsum);
  k_scan2<<<1, 1, 0, stream>>>(bsum, nb);
  k_scan3<<<(NN + 255)/256, 256, 0, stream>>>(stmp, bsum, deg, easum, offsets, cursor, meanattr);
  k_fill<<<(E2 + 255)/256, 256, 0, stream>>>(dstp, cursor, eid);
  k_ve<<<1, 64, 0, stream>>>(We1, a1e, We2, a2e, ve);

  k_proj1<<<NN/PR1, 256, 0, stream>>>(x, W1, a1s, a1d, h1, asrc1, adst1);
  k_agg1<<<NN/4, 256, 0, stream>>>(srcp, ea, meanattr, offsets, deg, eid,
                                   h1, asrc1, adst1, ve, b1, out1);
  k_proj2<<<NN/PR2, 256, 0, stream>>>(out1, W2, a2s, a2d, h2, asrc2, adst2);
  k_agg2<<<NN/4, 256, 0, stream>>>(srcp, ea, meanattr, offsets, deg, eid,
                                   h2, asrc2, adst2, ve, b2, out2);
  k_pool<<<GG, 256, 0, stream>>>(out2, batch, Wl, bl, (float*)d_out);
}

// Round 7
// 769.698 us; speedup vs baseline: 1.3142x; 1.3142x over previous
//
#include <hip/hip_runtime.h>
#include <math.h>

// Problem constants (match reference)
constexpr int NN   = 50000;    // nodes
constexpr int EE   = 1000000;  // edges (before self loops)
constexpr int E2   = EE + NN;  // edges incl self loops
constexpr int HEADS = 4;
constexpr int HID  = 64;
constexpr int GG   = 64;       // graphs
constexpr int NCLS = 2;
constexpr float NEG = 0.2f;

__device__ __forceinline__ float leaky(float v){ return v > 0.f ? v : NEG * v; }

// ---------------------------------------------------------------- CSR build
__global__ __launch_bounds__(256) void k_edge_count(const int* __restrict__ dst,
                                                    const float* __restrict__ ea,
                                                    int* __restrict__ deg,
                                                    float* __restrict__ easum){
  int e = blockIdx.x * 256 + threadIdx.x;
  if (e >= EE) return;
  int d = dst[e];
  atomicAdd(&deg[d], 1);
  atomicAdd(&easum[d*2+0], ea[e*2+0]);
  atomicAdd(&easum[d*2+1], ea[e*2+1]);
}

__global__ __launch_bounds__(1024) void k_scan1(const int* __restrict__ deg,
                                                int* __restrict__ tmp,
                                                int* __restrict__ bsum){
  __shared__ int s[1024];
  int t = threadIdx.x;
  int gid = blockIdx.x * 1024 + t;
  int v = (gid < NN) ? (deg[gid] + 1) : 0;   // +1 for self loop
  s[t] = v;
  __syncthreads();
  for (int off = 1; off < 1024; off <<= 1){
    int u = (t >= off) ? s[t - off] : 0;
    __syncthreads();
    s[t] += u;
    __syncthreads();
  }
  if (gid < NN) tmp[gid] = s[t];             // inclusive scan
  if (t == 1023) bsum[blockIdx.x] = s[1023];
}

__global__ void k_scan2(int* bsum, int nb){
  if (threadIdx.x == 0 && blockIdx.x == 0){
    int run = 0;
    for (int b = 0; b < nb; ++b){ int x = bsum[b]; bsum[b] = run; run += x; }
  }
}

__global__ __launch_bounds__(256) void k_scan3(const int* __restrict__ tmp,
                                               const int* __restrict__ bsum,
                                               const int* __restrict__ deg,
                                               const float* __restrict__ easum,
                                               int* __restrict__ offsets,
                                               int* __restrict__ cursor,
                                               float* __restrict__ meanattr){
  int i = blockIdx.x * 256 + threadIdx.x;
  if (i >= NN) return;
  int d = deg[i];
  int excl = tmp[i] - (d + 1) + bsum[i >> 10];
  offsets[i] = excl;
  cursor[i]  = excl;
  float c = fmaxf((float)d, 1.0f);           // fill_value='mean' semantics
  meanattr[i*2+0] = easum[i*2+0] / c;
  meanattr[i*2+1] = easum[i*2+1] / c;
}

__global__ __launch_bounds__(256) void k_fill(const int* __restrict__ dst,
                                              int* __restrict__ cursor,
                                              int* __restrict__ eid){
  int t = blockIdx.x * 256 + threadIdx.x;
  if (t < EE){
    int d = dst[t];
    int p = atomicAdd(&cursor[d], 1);
    eid[p] = t;
  } else if (t < E2){
    int i = t - EE;                          // self loop edge id = EE + i
    int p = atomicAdd(&cursor[i], 1);
    eid[p] = EE + i;
  }
}

// Fold edge-attr projection+attention into a [heads][2] vector:
// a_edge[e][h] = ea[e,0]*ve[h][0] + ea[e,1]*ve[h][1]
__global__ void k_ve(const float* __restrict__ We1, const float* __restrict__ a1e,
                     const float* __restrict__ We2, const float* __restrict__ a2e,
                     float* __restrict__ ve){
  int t = threadIdx.x;
  if (t < 8){
    int h = t >> 1, d = t & 1;
    float s = 0.f;
    for (int c = 0; c < HID; ++c) s += We1[d*256 + h*64 + c] * a1e[h*64 + c];
    ve[t] = s;                               // ve[h*2+d]
  } else if (t < 10){
    int d = t - 8;
    float s = 0.f;
    for (int c = 0; c < HID; ++c) s += We2[d*64 + c] * a2e[c];
    ve[8 + d] = s;                           // ve2[d]
  }
}

// ------------------------------------------------------- layer 1 projection
// h1 = x @ W1  ([N,64]@[64,256]).
// Block = 256 threads = 8 rows; thread t owns output col t for all 8 rows.
// W1 per-k coalesced from L1/L2; x rows in 2 KB LDS (broadcast reads).
// KEY (r5/r6 lesson): cap unroll + __launch_bounds__(256,4) so the compiler
// can't hoist the weight stream into VGPRs (256-VGPR cap killed occupancy).
constexpr int PR1 = 8;
__global__ __launch_bounds__(256, 4) void k_proj1(const float* __restrict__ x,
                                                  const float* __restrict__ W1,
                                                  const float* __restrict__ a1s,
                                                  const float* __restrict__ a1d,
                                                  float* __restrict__ h1,
                                                  float* __restrict__ asrc,
                                                  float* __restrict__ adst){
  __shared__ float xs[PR1][64];
  int t = threadIdx.x;
  int row0 = blockIdx.x * PR1;               // NN % PR1 == 0
  for (int i = t; i < PR1*64; i += 256)
    xs[i >> 6][i & 63] = x[row0*64 + i];
  __syncthreads();
  float acc[PR1][4] = {};
  #pragma unroll 2
  for (int k4 = 0; k4 < 16; ++k4){
    float wv0 = W1[(k4*4+0)*256 + t];
    float wv1 = W1[(k4*4+1)*256 + t];
    float wv2 = W1[(k4*4+2)*256 + t];
    float wv3 = W1[(k4*4+3)*256 + t];
    #pragma unroll
    for (int r = 0; r < PR1; ++r){
      float4 xq = *(const float4*)&xs[r][k4*4];  // same addr all lanes: broadcast
      acc[r][0] = fmaf(xq.x, wv0, acc[r][0]);
      acc[r][1] = fmaf(xq.y, wv1, acc[r][1]);
      acc[r][2] = fmaf(xq.z, wv2, acc[r][2]);
      acc[r][3] = fmaf(xq.w, wv3, acc[r][3]);
    }
  }
  int lane = t & 63, wave = t >> 6;          // wave == head (col t = head*64+ch)
  float as_w = a1s[t], ad_w = a1d[t];        // a1s flat [4*64]; col == flat idx
  #pragma unroll
  for (int r = 0; r < PR1; ++r){
    int row = row0 + r;
    float hv = (acc[r][0] + acc[r][1]) + (acc[r][2] + acc[r][3]);
    h1[row*256 + t] = hv;
    float ps = hv * as_w, pd = hv * ad_w;
    #pragma unroll
    for (int off = 32; off; off >>= 1){ ps += __shfl_xor(ps, off); pd += __shfl_xor(pd, off); }
    if (lane == 0){ asrc[row*4 + wave] = ps; adst[row*4 + wave] = pd; }
  }
}

// ----------------------------------------------- layer 1 softmax + aggregate
// One wave per node. Phase A: lane-parallel max over in-edges (logits for the
// first 64 edges cached in registers). Phase B: lane-parallel w=exp(al-mx).
// Phase C: serial gather where s/w come from __shfl register broadcast.
__global__ __launch_bounds__(256) void k_agg1(const int* __restrict__ src,
                                              const float* __restrict__ ea,
                                              const float* __restrict__ meanattr,
                                              const int* __restrict__ offsets,
                                              const int* __restrict__ deg,
                                              const int* __restrict__ eid,
                                              const float* __restrict__ h1,
                                              const float* __restrict__ asrc,
                                              const float* __restrict__ adst,
                                              const float* __restrict__ ve,
                                              const float* __restrict__ b1,
                                              float* __restrict__ out1){
  int node = blockIdx.x * 4 + (threadIdx.x >> 6);
  int lane = threadIdx.x & 63;
  int lo  = offsets[node];
  int cnt = deg[node] + 1;
  int h = lane >> 4;
  float ad0 = adst[node*4+0], ad1 = adst[node*4+1];
  float ad2 = adst[node*4+2], ad3 = adst[node*4+3];
  float v00 = ve[0], v01 = ve[1], v10 = ve[2], v11 = ve[3];
  float v20 = ve[4], v21 = ve[5], v30 = ve[6], v31 = ve[7];

  // Phase A: per-head segment max, lane-parallel; cache chunk-0 logits+src
  float mx0 = -INFINITY, mx1 = -INFINITY, mx2 = -INFINITY, mx3 = -INFINITY;
  float cal0 = 0.f, cal1 = 0.f, cal2 = 0.f, cal3 = 0.f;
  int   cs = 0;
  if (lane < cnt){
    int e = eid[lo + lane];
    int s; float e0, e1;
    if (e < EE){ s = src[e]; e0 = ea[e*2]; e1 = ea[e*2+1]; }
    else       { s = node;   e0 = meanattr[node*2]; e1 = meanattr[node*2+1]; }
    float s0 = asrc[s*4+0], s1 = asrc[s*4+1], s2 = asrc[s*4+2], s3 = asrc[s*4+3];
    cal0 = leaky(s0 + ad0 + e0*v00 + e1*v01);
    cal1 = leaky(s1 + ad1 + e0*v10 + e1*v11);
    cal2 = leaky(s2 + ad2 + e0*v20 + e1*v21);
    cal3 = leaky(s3 + ad3 + e0*v30 + e1*v31);
    cs = s;
    mx0 = cal0; mx1 = cal1; mx2 = cal2; mx3 = cal3;
  }
  for (int k = lane + 64; k < cnt; k += 64){   // essentially never taken (deg~20)
    int e = eid[lo + k];
    int s; float e0, e1;
    if (e < EE){ s = src[e]; e0 = ea[e*2]; e1 = ea[e*2+1]; }
    else       { s = node;   e0 = meanattr[node*2]; e1 = meanattr[node*2+1]; }
    float s0 = asrc[s*4+0], s1 = asrc[s*4+1], s2 = asrc[s*4+2], s3 = asrc[s*4+3];
    mx0 = fmaxf(mx0, leaky(s0 + ad0 + e0*v00 + e1*v01));
    mx1 = fmaxf(mx1, leaky(s1 + ad1 + e0*v10 + e1*v11));
    mx2 = fmaxf(mx2, leaky(s2 + ad2 + e0*v20 + e1*v21));
    mx3 = fmaxf(mx3, leaky(s3 + ad3 + e0*v30 + e1*v31));
  }
  #pragma unroll
  for (int off = 32; off; off >>= 1){
    mx0 = fmaxf(mx0, __shfl_xor(mx0, off));
    mx1 = fmaxf(mx1, __shfl_xor(mx1, off));
    mx2 = fmaxf(mx2, __shfl_xor(mx2, off));
    mx3 = fmaxf(mx3, __shfl_xor(mx3, off));
  }

  // Phases B+C per 64-edge chunk
  float4 acc = make_float4(0.f, 0.f, 0.f, 0.f);
  float den = 0.f;
  for (int base = 0; base < cnt; base += 64){
    int k = base + lane;
    float w0 = 0.f, w1 = 0.f, w2 = 0.f, w3 = 0.f;
    int sv = 0;
    if (k < cnt){
      float a0, a1, a2, a3; int s;
      if (base == 0){ s = cs; a0 = cal0; a1 = cal1; a2 = cal2; a3 = cal3; }
      else {
        int e = eid[lo + k];
        float e0, e1;
        if (e < EE){ s = src[e]; e0 = ea[e*2]; e1 = ea[e*2+1]; }
        else       { s = node;   e0 = meanattr[node*2]; e1 = meanattr[node*2+1]; }
        a0 = leaky(asrc[s*4+0] + ad0 + e0*v00 + e1*v01);
        a1 = leaky(asrc[s*4+1] + ad1 + e0*v10 + e1*v11);
        a2 = leaky(asrc[s*4+2] + ad2 + e0*v20 + e1*v21);
        a3 = leaky(asrc[s*4+3] + ad3 + e0*v30 + e1*v31);
      }
      w0 = __expf(a0 - mx0); w1 = __expf(a1 - mx1);
      w2 = __expf(a2 - mx2); w3 = __expf(a3 - mx3);
      sv = s;
    }
    int m = min(64, cnt - base);
    #pragma unroll 4
    for (int k2 = 0; k2 < m; ++k2){
      int   s  = __shfl(sv, k2);
      float q0 = __shfl(w0, k2);
      float q1 = __shfl(w1, k2);
      float q2 = __shfl(w2, k2);
      float q3 = __shfl(w3, k2);
      float w  = (h == 0) ? q0 : (h == 1) ? q1 : (h == 2) ? q2 : q3;
      float4 v = *(const float4*)&h1[s*256 + lane*4];
      den += w;
      acc.x = fmaf(w, v.x, acc.x);
      acc.y = fmaf(w, v.y, acc.y);
      acc.z = fmaf(w, v.z, acc.z);
      acc.w = fmaf(w, v.w, acc.w);
    }
  }
  float4 bb = *(const float4*)&b1[lane*4];
  float inv = 1.f / den;
  float4 o;
  o.x = fmaxf(fmaf(acc.x, inv, bb.x), 0.f);
  o.y = fmaxf(fmaf(acc.y, inv, bb.y), 0.f);
  o.z = fmaxf(fmaf(acc.z, inv, bb.z), 0.f);
  o.w = fmaxf(fmaf(acc.w, inv, bb.w), 0.f);
  *(float4*)&out1[node*256 + lane*4] = o;
}

// ------------------------------------------------------- layer 2 projection
// h2 = out1 @ W2  ([N,256]@[256,64]).
// Block = 256 threads = 16 rows; wave owns 4 rows, lane = output col.
// W2 per-k coalesced from L1/L2 (amortized over 16 rows); out1 rows in
// 16 KB LDS read as broadcast b128. acc[4][4] = 16 indep FMA chains/lane.
// Unroll capped + __launch_bounds__(256,4): keep VGPR < 128 (r6 lesson).
constexpr int PR2 = 16;
__global__ __launch_bounds__(256, 4) void k_proj2(const float* __restrict__ out1,
                                                  const float* __restrict__ W2,
                                                  const float* __restrict__ a2s,
                                                  const float* __restrict__ a2d,
                                                  float* __restrict__ h2,
                                                  float* __restrict__ asrc,
                                                  float* __restrict__ adst){
  __shared__ float xs[PR2][256];             // 16 KB
  int t = threadIdx.x;
  int row0 = blockIdx.x * PR2;               // NN % PR2 == 0
  for (int i = t*4; i < PR2*256; i += 1024)
    *(float4*)&xs[i >> 8][i & 255] = *(const float4*)&out1[row0*256 + i];
  __syncthreads();
  int lane = t & 63, wave = t >> 6;
  int rbase = wave * 4;
  float acc[4][4] = {};
  #pragma unroll 2
  for (int k4 = 0; k4 < 64; ++k4){
    float wv0 = W2[(k4*4+0)*64 + lane];
    float wv1 = W2[(k4*4+1)*64 + lane];
    float wv2 = W2[(k4*4+2)*64 + lane];
    float wv3 = W2[(k4*4+3)*64 + lane];
    #pragma unroll
    for (int r = 0; r < 4; ++r){
      float4 xq = *(const float4*)&xs[rbase + r][k4*4];  // broadcast
      acc[r][0] = fmaf(xq.x, wv0, acc[r][0]);
      acc[r][1] = fmaf(xq.y, wv1, acc[r][1]);
      acc[r][2] = fmaf(xq.z, wv2, acc[r][2]);
      acc[r][3] = fmaf(xq.w, wv3, acc[r][3]);
    }
  }
  float aw_s = a2s[lane], aw_d = a2d[lane];
  #pragma unroll
  for (int r = 0; r < 4; ++r){
    int row = row0 + rbase + r;
    float hv = (acc[r][0] + acc[r][1]) + (acc[r][2] + acc[r][3]);
    h2[row*64 + lane] = hv;
    float ps = hv * aw_s, pd = hv * aw_d;
    #pragma unroll
    for (int off = 32; off; off >>= 1){ ps += __shfl_xor(ps, off); pd += __shfl_xor(pd, off); }
    if (lane == 0){ asrc[row] = ps; adst[row] = pd; }
  }
}

// ----------------------------------------------- layer 2 softmax + aggregate
__global__ __launch_bounds__(256) void k_agg2(const int* __restrict__ src,
                                              const float* __restrict__ ea,
                                              const float* __restrict__ meanattr,
                                              const int* __restrict__ offsets,
                                              const int* __restrict__ deg,
                                              const int* __restrict__ eid,
                                              const float* __restrict__ h2,
                                              const float* __restrict__ asrc,
                                              const float* __restrict__ adst,
                                              const float* __restrict__ ve,
                                              const float* __restrict__ b2,
                                              float* __restrict__ out2){
  int node = blockIdx.x * 4 + (threadIdx.x >> 6);
  int lane = threadIdx.x & 63;
  int lo  = offsets[node];
  int cnt = deg[node] + 1;
  float adI = adst[node];
  float v0 = ve[8], v1 = ve[9];

  float mx = -INFINITY, cal = 0.f;
  int cs = 0;
  if (lane < cnt){
    int e = eid[lo + lane];
    int s; float e0, e1;
    if (e < EE){ s = src[e]; e0 = ea[e*2]; e1 = ea[e*2+1]; }
    else       { s = node;   e0 = meanattr[node*2]; e1 = meanattr[node*2+1]; }
    cal = leaky(asrc[s] + adI + e0*v0 + e1*v1);
    cs = s;
    mx = cal;
  }
  for (int k = lane + 64; k < cnt; k += 64){
    int e = eid[lo + k];
    int s; float e0, e1;
    if (e < EE){ s = src[e]; e0 = ea[e*2]; e1 = ea[e*2+1]; }
    else       { s = node;   e0 = meanattr[node*2]; e1 = meanattr[node*2+1]; }
    mx = fmaxf(mx, leaky(asrc[s] + adI + e0*v0 + e1*v1));
  }
  #pragma unroll
  for (int off = 32; off; off >>= 1) mx = fmaxf(mx, __shfl_xor(mx, off));

  float acc = 0.f, den = 0.f;
  for (int base = 0; base < cnt; base += 64){
    int k = base + lane;
    float w = 0.f; int sv = 0;
    if (k < cnt){
      float a; int s;
      if (base == 0){ s = cs; a = cal; }
      else {
        int e = eid[lo + k];
        float e0, e1;
        if (e < EE){ s = src[e]; e0 = ea[e*2]; e1 = ea[e*2+1]; }
        else       { s = node;   e0 = meanattr[node*2]; e1 = meanattr[node*2+1]; }
        a = leaky(asrc[s] + adI + e0*v0 + e1*v1);
      }
      w = __expf(a - mx);
      sv = s;
    }
    int m = min(64, cnt - base);
    #pragma unroll 4
    for (int k2 = 0; k2 < m; ++k2){
      int   s  = __shfl(sv, k2);
      float ww = __shfl(w,  k2);
      den += ww;
      acc = fmaf(ww, h2[s*64 + lane], acc);
    }
  }
  out2[node*64 + lane] = fmaxf(acc / den + b2[lane], 0.f);
}

// ------------------------------------------------------- pool + classifier
__global__ __launch_bounds__(256) void k_pool(const float* __restrict__ out2,
                                              const int* __restrict__ batch,
                                              const float* __restrict__ Wl,
                                              const float* __restrict__ bl,
                                              float* __restrict__ out){
  __shared__ float red[4][64];
  __shared__ float sh_mean[64];
  int g = blockIdx.x;
  int t = threadIdx.x, lane = t & 63, wave = t >> 6;
  // batch is sorted: binary search graph range
  int lo = 0, hi = NN;
  while (lo < hi){ int m = (lo + hi) >> 1; if (batch[m] < g) lo = m + 1; else hi = m; }
  int start = lo;
  lo = start; hi = NN;
  while (lo < hi){ int m = (lo + hi) >> 1; if (batch[m] < g + 1) lo = m + 1; else hi = m; }
  int end = lo;
  float acc = 0.f;
  for (int n = start + wave; n < end; n += 4) acc += out2[n*64 + lane];
  red[wave][lane] = acc;
  __syncthreads();
  if (wave == 0){
    float s = red[0][lane] + red[1][lane] + red[2][lane] + red[3][lane];
    sh_mean[lane] = s / fmaxf((float)(end - start), 1.0f);
  }
  __syncthreads();
  if (t < NCLS){
    float o = bl[t];
    for (int c = 0; c < HID; ++c) o = fmaf(sh_mean[c], Wl[c*NCLS + t], o);
    out[g*NCLS + t] = o;
  }
}

// ---------------------------------------------------------------- launcher
extern "C" void kernel_launch(void* const* d_in, const int* in_sizes, int n_in,
                              void* d_out, int out_size, void* d_ws, size_t ws_size,
                              hipStream_t stream){
  const float* x     = (const float*)d_in[0];
  const int*   ei    = (const int*)  d_in[1];
  const float* ea    = (const float*)d_in[2];
  const int*   batch = (const int*)  d_in[3];
  const float* W1    = (const float*)d_in[4];
  const float* a1s   = (const float*)d_in[5];
  const float* a1d   = (const float*)d_in[6];
  const float* We1   = (const float*)d_in[7];
  const float* a1e   = (const float*)d_in[8];
  const float* b1    = (const float*)d_in[9];
  const float* W2    = (const float*)d_in[10];
  const float* a2s   = (const float*)d_in[11];
  const float* a2d   = (const float*)d_in[12];
  const float* We2   = (const float*)d_in[13];
  const float* a2e   = (const float*)d_in[14];
  const float* b2    = (const float*)d_in[15];
  const float* Wl    = (const float*)d_in[16];
  const float* bl    = (const float*)d_in[17];
  const int* srcp = ei;        // edge_index[0]
  const int* dstp = ei + EE;   // edge_index[1]

  char* base = (char*)d_ws;
  size_t off = 0;
  auto alloc = [&](size_t bytes) -> char* {
    char* p = base + off;
    off = (off + bytes + 255) & ~(size_t)255;
    return p;
  };
  // Large persistent regions
  float* h1   = (float*)alloc((size_t)NN*256*4);   // 51.2 MB (layer-1 proj)
  float* out1 = (float*)alloc((size_t)NN*256*4);   // 51.2 MB (layer-1 out)
  // h2/out2 alias the h1 region: h1 is dead once k_agg1 completes, and
  // k_proj2 (writes h2) / k_agg2 (writes out2) run strictly after it.
  float* h2   = (float*)h1;                        // NN*64*4 = 12.8 MB
  float* out2 = (float*)(h1 + (size_t)NN*64);      // next 12.8 MB of h1 region
  // Small regions
  float* asrc1    = (float*)alloc((size_t)NN*4*4);
  float* adst1    = (float*)alloc((size_t)NN*4*4);
  float* asrc2    = (float*)alloc((size_t)NN*4);
  float* adst2    = (float*)alloc((size_t)NN*4);
  float* easum    = (float*)alloc((size_t)NN*2*4);
  float* meanattr = (float*)alloc((size_t)NN*2*4);
  int*   deg      = (int*)  alloc((size_t)NN*4);
  int*   offsets  = (int*)  alloc((size_t)NN*4);
  int*   cursor   = (int*)  alloc((size_t)NN*4);
  int*   eid      = (int*)  alloc((size_t)E2*4);
  int*   stmp     = (int*)  alloc((size_t)NN*4);
  int*   bsum     = (int*)  alloc(64*4);
  float* ve       = (float*)alloc(16*4);
  if (off > ws_size) return;   // workspace too small: fail loudly (poisoned out)

  hipMemsetAsync(deg,   0, (size_t)NN*4,   stream);
  hipMemsetAsync(easum, 0, (size_t)NN*2*4, stream);

  int nb = (NN + 1023) / 1024;
  k_edge_count<<<(EE + 255)/256, 256, 0, stream>>>(dstp, ea, deg, easum);
  k_scan1<<<nb, 1024, 0, stream>>>(deg, stmp, bsum);
  k_scan2<<<1, 1, 0, stream>>>(bsum, nb);
  k_scan3<<<(NN + 255)/256, 256, 0, stream>>>(stmp, bsum, deg, easum, offsets, cursor, meanattr);
  k_fill<<<(E2 + 255)/256, 256, 0, stream>>>(dstp, cursor, eid);
  k_ve<<<1, 64, 0, stream>>>(We1, a1e, We2, a2e, ve);

  k_proj1<<<NN/PR1, 256, 0, stream>>>(x, W1, a1s, a1d, h1, asrc1, adst1);
  k_agg1<<<NN/4, 256, 0, stream>>>(srcp, ea, meanattr, offsets, deg, eid,
                                   h1, asrc1, adst1, ve, b1, out1);
  k_proj2<<<NN/PR2, 256, 0, stream>>>(out1, W2, a2s, a2d, h2, asrc2, adst2);
  k_agg2<<<NN/4, 256, 0, stream>>>(srcp, ea, meanattr, offsets, deg, eid,
                                   h2, asrc2, adst2, ve, b2, out2);
  k_pool<<<GG, 256, 0, stream>>>(out2, batch, Wl, bl, (float*)d_out);
}

// Round 9
// 745.870 us; speedup vs baseline: 1.3561x; 1.0319x over previous
//
#include <hip/hip_runtime.h>
#include <math.h>

// Problem constants (match reference)
constexpr int NN   = 50000;    // nodes
constexpr int EE   = 1000000;  // edges (before self loops)
constexpr int E2   = EE + NN;  // edges incl self loops
constexpr int HEADS = 4;
constexpr int HID  = 64;
constexpr int GG   = 64;       // graphs
constexpr int NCLS = 2;
constexpr float NEG = 0.2f;

__device__ __forceinline__ float leaky(float v){ return v > 0.f ? v : NEG * v; }

// ---------------------------------------------------------------- CSR build
__global__ __launch_bounds__(256) void k_edge_count(const int* __restrict__ dst,
                                                    const float* __restrict__ ea,
                                                    int* __restrict__ deg,
                                                    float* __restrict__ easum){
  int e = blockIdx.x * 256 + threadIdx.x;
  if (e >= EE) return;
  int d = dst[e];
  atomicAdd(&deg[d], 1);
  atomicAdd(&easum[d*2+0], ea[e*2+0]);
  atomicAdd(&easum[d*2+1], ea[e*2+1]);
}

__global__ __launch_bounds__(1024) void k_scan1(const int* __restrict__ deg,
                                                int* __restrict__ tmp,
                                                int* __restrict__ bsum){
  __shared__ int s[1024];
  int t = threadIdx.x;
  int gid = blockIdx.x * 1024 + t;
  int v = (gid < NN) ? (deg[gid] + 1) : 0;   // +1 for self loop
  s[t] = v;
  __syncthreads();
  for (int off = 1; off < 1024; off <<= 1){
    int u = (t >= off) ? s[t - off] : 0;
    __syncthreads();
    s[t] += u;
    __syncthreads();
  }
  if (gid < NN) tmp[gid] = s[t];             // inclusive scan
  if (t == 1023) bsum[blockIdx.x] = s[1023];
}

__global__ void k_scan2(int* bsum, int nb){
  if (threadIdx.x == 0 && blockIdx.x == 0){
    int run = 0;
    for (int b = 0; b < nb; ++b){ int x = bsum[b]; bsum[b] = run; run += x; }
  }
}

__global__ __launch_bounds__(256) void k_scan3(const int* __restrict__ tmp,
                                               const int* __restrict__ bsum,
                                               const int* __restrict__ deg,
                                               const float* __restrict__ easum,
                                               int* __restrict__ offsets,
                                               int* __restrict__ cursor,
                                               float* __restrict__ meanattr){
  int i = blockIdx.x * 256 + threadIdx.x;
  if (i >= NN) return;
  int d = deg[i];
  int excl = tmp[i] - (d + 1) + bsum[i >> 10];
  offsets[i] = excl;
  cursor[i]  = excl;
  float c = fmaxf((float)d, 1.0f);           // fill_value='mean' semantics
  meanattr[i*2+0] = easum[i*2+0] / c;
  meanattr[i*2+1] = easum[i*2+1] / c;
}

__global__ __launch_bounds__(256) void k_fill(const int* __restrict__ dst,
                                              int* __restrict__ cursor,
                                              int* __restrict__ eid){
  int t = blockIdx.x * 256 + threadIdx.x;
  if (t < EE){
    int d = dst[t];
    int p = atomicAdd(&cursor[d], 1);
    eid[p] = t;
  } else if (t < E2){
    int i = t - EE;                          // self loop edge id = EE + i
    int p = atomicAdd(&cursor[i], 1);
    eid[p] = EE + i;
  }
}

// Fold edge-attr projection+attention into a [heads][2] vector:
// a_edge[e][h] = ea[e,0]*ve[h][0] + ea[e,1]*ve[h][1]
__global__ void k_ve(const float* __restrict__ We1, const float* __restrict__ a1e,
                     const float* __restrict__ We2, const float* __restrict__ a2e,
                     float* __restrict__ ve){
  int t = threadIdx.x;
  if (t < 8){
    int h = t >> 1, d = t & 1;
    float s = 0.f;
    for (int c = 0; c < HID; ++c) s += We1[d*256 + h*64 + c] * a1e[h*64 + c];
    ve[t] = s;                               // ve[h*2+d]
  } else if (t < 10){
    int d = t - 8;
    float s = 0.f;
    for (int c = 0; c < HID; ++c) s += We2[d*64 + c] * a2e[c];
    ve[8 + d] = s;                           // ve2[d]
  }
}

// ------------------------------------------------------- layer 1 projection
// (r7: verified good — out of top-5). Unroll capped + launch_bounds(256,4).
constexpr int PR1 = 8;
__global__ __launch_bounds__(256, 4) void k_proj1(const float* __restrict__ x,
                                                  const float* __restrict__ W1,
                                                  const float* __restrict__ a1s,
                                                  const float* __restrict__ a1d,
                                                  float* __restrict__ h1,
                                                  float* __restrict__ asrc,
                                                  float* __restrict__ adst){
  __shared__ float xs[PR1][64];
  int t = threadIdx.x;
  int row0 = blockIdx.x * PR1;               // NN % PR1 == 0
  for (int i = t; i < PR1*64; i += 256)
    xs[i >> 6][i & 63] = x[row0*64 + i];
  __syncthreads();
  float acc[PR1][4] = {};
  #pragma unroll 2
  for (int k4 = 0; k4 < 16; ++k4){
    float wv0 = W1[(k4*4+0)*256 + t];
    float wv1 = W1[(k4*4+1)*256 + t];
    float wv2 = W1[(k4*4+2)*256 + t];
    float wv3 = W1[(k4*4+3)*256 + t];
    #pragma unroll
    for (int r = 0; r < PR1; ++r){
      float4 xq = *(const float4*)&xs[r][k4*4];  // same addr all lanes: broadcast
      acc[r][0] = fmaf(xq.x, wv0, acc[r][0]);
      acc[r][1] = fmaf(xq.y, wv1, acc[r][1]);
      acc[r][2] = fmaf(xq.z, wv2, acc[r][2]);
      acc[r][3] = fmaf(xq.w, wv3, acc[r][3]);
    }
  }
  int lane = t & 63, wave = t >> 6;          // wave == head (col t = head*64+ch)
  float as_w = a1s[t], ad_w = a1d[t];        // a1s flat [4*64]; col == flat idx
  #pragma unroll
  for (int r = 0; r < PR1; ++r){
    int row = row0 + r;
    float hv = (acc[r][0] + acc[r][1]) + (acc[r][2] + acc[r][3]);
    h1[row*256 + t] = hv;
    float ps = hv * as_w, pd = hv * ad_w;
    #pragma unroll
    for (int off = 32; off; off >>= 1){ ps += __shfl_xor(ps, off); pd += __shfl_xor(pd, off); }
    if (lane == 0){ asrc[row*4 + wave] = ps; adst[row*4 + wave] = pd; }
  }
}

// ----------------------------------------------- layer 1 softmax + aggregate
// One wave per node. r8 change: the serial gather loop's per-edge broadcast
// now comes from per-wave LDS staging (1 ds_read_b64/edge, same-addr
// broadcast within head group, 4 banks across heads = conflict-free),
// replacing 5 ds_bpermute/edge. DS-pipe ops per node: ~105 -> ~23.
__global__ __launch_bounds__(256) void k_agg1(const int* __restrict__ src,
                                              const float* __restrict__ ea,
                                              const float* __restrict__ meanattr,
                                              const int* __restrict__ offsets,
                                              const int* __restrict__ deg,
                                              const int* __restrict__ eid,
                                              const float* __restrict__ h1,
                                              const float* __restrict__ asrc,
                                              const float* __restrict__ adst,
                                              const float* __restrict__ ve,
                                              const float* __restrict__ b1,
                                              float* __restrict__ out1){
  __shared__ float2 swp[4][64][4];           // [wave][edge-slot][head] = {s,w}
  int wave = threadIdx.x >> 6;
  int node = blockIdx.x * 4 + wave;
  int lane = threadIdx.x & 63;
  int lo  = offsets[node];
  int cnt = deg[node] + 1;
  int h = lane >> 4;
  float ad0 = adst[node*4+0], ad1 = adst[node*4+1];
  float ad2 = adst[node*4+2], ad3 = adst[node*4+3];
  float v00 = ve[0], v01 = ve[1], v10 = ve[2], v11 = ve[3];
  float v20 = ve[4], v21 = ve[5], v30 = ve[6], v31 = ve[7];

  // Phase A: per-head segment max, lane-parallel; cache chunk-0 logits+src
  float mx0 = -INFINITY, mx1 = -INFINITY, mx2 = -INFINITY, mx3 = -INFINITY;
  float cal0 = 0.f, cal1 = 0.f, cal2 = 0.f, cal3 = 0.f;
  int   cs = 0;
  if (lane < cnt){
    int e = eid[lo + lane];
    int s; float e0, e1;
    if (e < EE){ s = src[e]; e0 = ea[e*2]; e1 = ea[e*2+1]; }
    else       { s = node;   e0 = meanattr[node*2]; e1 = meanattr[node*2+1]; }
    float s0 = asrc[s*4+0], s1 = asrc[s*4+1], s2 = asrc[s*4+2], s3 = asrc[s*4+3];
    cal0 = leaky(s0 + ad0 + e0*v00 + e1*v01);
    cal1 = leaky(s1 + ad1 + e0*v10 + e1*v11);
    cal2 = leaky(s2 + ad2 + e0*v20 + e1*v21);
    cal3 = leaky(s3 + ad3 + e0*v30 + e1*v31);
    cs = s;
    mx0 = cal0; mx1 = cal1; mx2 = cal2; mx3 = cal3;
  }
  for (int k = lane + 64; k < cnt; k += 64){   // essentially never taken (deg~20)
    int e = eid[lo + k];
    int s; float e0, e1;
    if (e < EE){ s = src[e]; e0 = ea[e*2]; e1 = ea[e*2+1]; }
    else       { s = node;   e0 = meanattr[node*2]; e1 = meanattr[node*2+1]; }
    float s0 = asrc[s*4+0], s1 = asrc[s*4+1], s2 = asrc[s*4+2], s3 = asrc[s*4+3];
    mx0 = fmaxf(mx0, leaky(s0 + ad0 + e0*v00 + e1*v01));
    mx1 = fmaxf(mx1, leaky(s1 + ad1 + e0*v10 + e1*v11));
    mx2 = fmaxf(mx2, leaky(s2 + ad2 + e0*v20 + e1*v21));
    mx3 = fmaxf(mx3, leaky(s3 + ad3 + e0*v30 + e1*v31));
  }
  #pragma unroll
  for (int off = 32; off; off >>= 1){
    mx0 = fmaxf(mx0, __shfl_xor(mx0, off));
    mx1 = fmaxf(mx1, __shfl_xor(mx1, off));
    mx2 = fmaxf(mx2, __shfl_xor(mx2, off));
    mx3 = fmaxf(mx3, __shfl_xor(mx3, off));
  }

  // Phases B+C per 64-edge chunk
  float4 acc = make_float4(0.f, 0.f, 0.f, 0.f);
  float den = 0.f;
  for (int base = 0; base < cnt; base += 64){
    int k = base + lane;
    float w0 = 0.f, w1 = 0.f, w2 = 0.f, w3 = 0.f;
    int sv = 0;
    if (k < cnt){
      float a0, a1, a2, a3; int s;
      if (base == 0){ s = cs; a0 = cal0; a1 = cal1; a2 = cal2; a3 = cal3; }
      else {
        int e = eid[lo + k];
        float e0, e1;
        if (e < EE){ s = src[e]; e0 = ea[e*2]; e1 = ea[e*2+1]; }
        else       { s = node;   e0 = meanattr[node*2]; e1 = meanattr[node*2+1]; }
        a0 = leaky(asrc[s*4+0] + ad0 + e0*v00 + e1*v01);
        a1 = leaky(asrc[s*4+1] + ad1 + e0*v10 + e1*v11);
        a2 = leaky(asrc[s*4+2] + ad2 + e0*v20 + e1*v21);
        a3 = leaky(asrc[s*4+3] + ad3 + e0*v30 + e1*v31);
      }
      w0 = __expf(a0 - mx0); w1 = __expf(a1 - mx1);
      w2 = __expf(a2 - mx2); w3 = __expf(a3 - mx3);
      sv = s;
    }
    // stage {src, w[head]} per edge-slot (2x ds_write_b128 per lane)
    float sb = __int_as_float(sv);
    *(float4*)&swp[wave][lane][0] = make_float4(sb, w0, sb, w1);
    *(float4*)&swp[wave][lane][2] = make_float4(sb, w2, sb, w3);
    int m = min(64, cnt - base);
    #pragma unroll 4
    for (int k2 = 0; k2 < m; ++k2){
      float2 pr = swp[wave][k2][h];          // 1 ds_read_b64, broadcast in head grp
      int   s = __float_as_int(pr.x);
      float w = pr.y;
      float4 v = *(const float4*)&h1[s*256 + lane*4];
      den += w;
      acc.x = fmaf(w, v.x, acc.x);
      acc.y = fmaf(w, v.y, acc.y);
      acc.z = fmaf(w, v.z, acc.z);
      acc.w = fmaf(w, v.w, acc.w);
    }
  }
  float4 bb = *(const float4*)&b1[lane*4];
  float inv = 1.f / den;
  float4 o;
  o.x = fmaxf(fmaf(acc.x, inv, bb.x), 0.f);
  o.y = fmaxf(fmaf(acc.y, inv, bb.y), 0.f);
  o.z = fmaxf(fmaf(acc.z, inv, bb.z), 0.f);
  o.w = fmaxf(fmaf(acc.w, inv, bb.w), 0.f);
  *(float4*)&out1[node*256 + lane*4] = o;
}

// ------------------------------------------------------- layer 2 projection
// (r7: verified good — out of top-5.)
constexpr int PR2 = 16;
__global__ __launch_bounds__(256, 4) void k_proj2(const float* __restrict__ out1,
                                                  const float* __restrict__ W2,
                                                  const float* __restrict__ a2s,
                                                  const float* __restrict__ a2d,
                                                  float* __restrict__ h2,
                                                  float* __restrict__ asrc,
                                                  float* __restrict__ adst){
  __shared__ float xs[PR2][256];             // 16 KB
  int t = threadIdx.x;
  int row0 = blockIdx.x * PR2;               // NN % PR2 == 0
  for (int i = t*4; i < PR2*256; i += 1024)
    *(float4*)&xs[i >> 8][i & 255] = *(const float4*)&out1[row0*256 + i];
  __syncthreads();
  int lane = t & 63, wave = t >> 6;
  int rbase = wave * 4;
  float acc[4][4] = {};
  #pragma unroll 2
  for (int k4 = 0; k4 < 64; ++k4){
    float wv0 = W2[(k4*4+0)*64 + lane];
    float wv1 = W2[(k4*4+1)*64 + lane];
    float wv2 = W2[(k4*4+2)*64 + lane];
    float wv3 = W2[(k4*4+3)*64 + lane];
    #pragma unroll
    for (int r = 0; r < 4; ++r){
      float4 xq = *(const float4*)&xs[rbase + r][k4*4];  // broadcast
      acc[r][0] = fmaf(xq.x, wv0, acc[r][0]);
      acc[r][1] = fmaf(xq.y, wv1, acc[r][1]);
      acc[r][2] = fmaf(xq.z, wv2, acc[r][2]);
      acc[r][3] = fmaf(xq.w, wv3, acc[r][3]);
    }
  }
  float aw_s = a2s[lane], aw_d = a2d[lane];
  #pragma unroll
  for (int r = 0; r < 4; ++r){
    int row = row0 + rbase + r;
    float hv = (acc[r][0] + acc[r][1]) + (acc[r][2] + acc[r][3]);
    h2[row*64 + lane] = hv;
    float ps = hv * aw_s, pd = hv * aw_d;
    #pragma unroll
    for (int off = 32; off; off >>= 1){ ps += __shfl_xor(ps, off); pd += __shfl_xor(pd, off); }
    if (lane == 0){ asrc[row] = ps; adst[row] = pd; }
  }
}

// ----------------------------------------------- layer 2 softmax + aggregate
// r8: same LDS-staging swap as k_agg1 (2 shfl/edge -> 1 uniform ds_read_b64).
__global__ __launch_bounds__(256) void k_agg2(const int* __restrict__ src,
                                              const float* __restrict__ ea,
                                              const float* __restrict__ meanattr,
                                              const int* __restrict__ offsets,
                                              const int* __restrict__ deg,
                                              const int* __restrict__ eid,
                                              const float* __restrict__ h2,
                                              const float* __restrict__ asrc,
                                              const float* __restrict__ adst,
                                              const float* __restrict__ ve,
                                              const float* __restrict__ b2,
                                              float* __restrict__ out2){
  __shared__ float2 st2[4][64];              // [wave][edge-slot] = {s,w}
  int wave = threadIdx.x >> 6;
  int node = blockIdx.x * 4 + wave;
  int lane = threadIdx.x & 63;
  int lo  = offsets[node];
  int cnt = deg[node] + 1;
  float adI = adst[node];
  float v0 = ve[8], v1 = ve[9];

  float mx = -INFINITY, cal = 0.f;
  int cs = 0;
  if (lane < cnt){
    int e = eid[lo + lane];
    int s; float e0, e1;
    if (e < EE){ s = src[e]; e0 = ea[e*2]; e1 = ea[e*2+1]; }
    else       { s = node;   e0 = meanattr[node*2]; e1 = meanattr[node*2+1]; }
    cal = leaky(asrc[s] + adI + e0*v0 + e1*v1);
    cs = s;
    mx = cal;
  }
  for (int k = lane + 64; k < cnt; k += 64){
    int e = eid[lo + k];
    int s; float e0, e1;
    if (e < EE){ s = src[e]; e0 = ea[e*2]; e1 = ea[e*2+1]; }
    else       { s = node;   e0 = meanattr[node*2]; e1 = meanattr[node*2+1]; }
    mx = fmaxf(mx, leaky(asrc[s] + adI + e0*v0 + e1*v1));
  }
  #pragma unroll
  for (int off = 32; off; off >>= 1) mx = fmaxf(mx, __shfl_xor(mx, off));

  float acc = 0.f, den = 0.f;
  for (int base = 0; base < cnt; base += 64){
    int k = base + lane;
    float w = 0.f; int sv = 0;
    if (k < cnt){
      float a; int s;
      if (base == 0){ s = cs; a = cal; }
      else {
        int e = eid[lo + k];
        float e0, e1;
        if (e < EE){ s = src[e]; e0 = ea[e*2]; e1 = ea[e*2+1]; }
        else       { s = node;   e0 = meanattr[node*2]; e1 = meanattr[node*2+1]; }
        a = leaky(asrc[s] + adI + e0*v0 + e1*v1);
      }
      w = __expf(a - mx);
      sv = s;
    }
    st2[wave][lane] = make_float2(__int_as_float(sv), w);
    int m = min(64, cnt - base);
    #pragma unroll 4
    for (int k2 = 0; k2 < m; ++k2){
      float2 pr = st2[wave][k2];             // uniform addr: broadcast read
      int   s  = __float_as_int(pr.x);
      float ww = pr.y;
      den += ww;
      acc = fmaf(ww, h2[s*64 + lane], acc);
    }
  }
  out2[node*64 + lane] = fmaxf(acc / den + b2[lane], 0.f);
}

// ------------------------------------------------------- pool + classifier
__global__ __launch_bounds__(256) void k_pool(const float* __restrict__ out2,
                                              const int* __restrict__ batch,
                                              const float* __restrict__ Wl,
                                              const float* __restrict__ bl,
                                              float* __restrict__ out){
  __shared__ float red[4][64];
  __shared__ float sh_mean[64];
  int g = blockIdx.x;
  int t = threadIdx.x, lane = t & 63, wave = t >> 6;
  // batch is sorted: binary search graph range
  int lo = 0, hi = NN;
  while (lo < hi){ int m = (lo + hi) >> 1; if (batch[m] < g) lo = m + 1; else hi = m; }
  int start = lo;
  lo = start; hi = NN;
  while (lo < hi){ int m = (lo + hi) >> 1; if (batch[m] < g + 1) lo = m + 1; else hi = m; }
  int end = lo;
  float acc = 0.f;
  for (int n = start + wave; n < end; n += 4) acc += out2[n*64 + lane];
  red[wave][lane] = acc;
  __syncthreads();
  if (wave == 0){
    float s = red[0][lane] + red[1][lane] + red[2][lane] + red[3][lane];
    sh_mean[lane] = s / fmaxf((float)(end - start), 1.0f);
  }
  __syncthreads();
  if (t < NCLS){
    float o = bl[t];
    for (int c = 0; c < HID; ++c) o = fmaf(sh_mean[c], Wl[c*NCLS + t], o);
    out[g*NCLS + t] = o;
  }
}

// ---------------------------------------------------------------- launcher
extern "C" void kernel_launch(void* const* d_in, const int* in_sizes, int n_in,
                              void* d_out, int out_size, void* d_ws, size_t ws_size,
                              hipStream_t stream){
  const float* x     = (const float*)d_in[0];
  const int*   ei    = (const int*)  d_in[1];
  const float* ea    = (const float*)d_in[2];
  const int*   batch = (const int*)  d_in[3];
  const float* W1    = (const float*)d_in[4];
  const float* a1s   = (const float*)d_in[5];
  const float* a1d   = (const float*)d_in[6];
  const float* We1   = (const float*)d_in[7];
  const float* a1e   = (const float*)d_in[8];
  const float* b1    = (const float*)d_in[9];
  const float* W2    = (const float*)d_in[10];
  const float* a2s   = (const float*)d_in[11];
  const float* a2d   = (const float*)d_in[12];
  const float* We2   = (const float*)d_in[13];
  const float* a2e   = (const float*)d_in[14];
  const float* b2    = (const float*)d_in[15];
  const float* Wl    = (const float*)d_in[16];
  const float* bl    = (const float*)d_in[17];
  const int* srcp = ei;        // edge_index[0]
  const int* dstp = ei + EE;   // edge_index[1]

  char* base = (char*)d_ws;
  size_t off = 0;
  auto alloc = [&](size_t bytes) -> char* {
    char* p = base + off;
    off = (off + bytes + 255) & ~(size_t)255;
    return p;
  };
  // Large persistent regions
  float* h1   = (float*)alloc((size_t)NN*256*4);   // 51.2 MB (layer-1 proj)
  float* out1 = (float*)alloc((size_t)NN*256*4);   // 51.2 MB (layer-1 out)
  // h2/out2 alias the h1 region: h1 is dead once k_agg1 completes, and
  // k_proj2 (writes h2) / k_agg2 (writes out2) run strictly after it.
  float* h2   = (float*)h1;                        // NN*64*4 = 12.8 MB
  float* out2 = (float*)(h1 + (size_t)NN*64);      // next 12.8 MB of h1 region
  // Small regions
  float* asrc1    = (float*)alloc((size_t)NN*4*4);
  float* adst1    = (float*)alloc((size_t)NN*4*4);
  float* asrc2    = (float*)alloc((size_t)NN*4);
  float* adst2    = (float*)alloc((size_t)NN*4);
  float* easum    = (float*)alloc((size_t)NN*2*4);
  float* meanattr = (float*)alloc((size_t)NN*2*4);
  int*   deg      = (int*)  alloc((size_t)NN*4);
  int*   offsets  = (int*)  alloc((size_t)NN*4);
  int*   cursor   = (int*)  alloc((size_t)NN*4);
  int*   eid      = (int*)  alloc((size_t)E2*4);
  int*   stmp     = (int*)  alloc((size_t)NN*4);
  int*   bsum     = (int*)  alloc(64*4);
  float* ve       = (float*)alloc(16*4);
  if (off > ws_size) return;   // workspace too small: fail loudly (poisoned out)

  hipMemsetAsync(deg,   0, (size_t)NN*4,   stream);
  hipMemsetAsync(easum, 0, (size_t)NN*2*4, stream);

  int nb = (NN + 1023) / 1024;
  k_edge_count<<<(EE + 255)/256, 256, 0, stream>>>(dstp, ea, deg, easum);
  k_scan1<<<nb, 1024, 0, stream>>>(deg, stmp, bsum);
  k_scan2<<<1, 1, 0, stream>>>(bsum, nb);
  k_scan3<<<(NN + 255)/256, 256, 0, stream>>>(stmp, bsum, deg, easum, offsets, cursor, meanattr);
  k_fill<<<(E2 + 255)/256, 256, 0, stream>>>(dstp, cursor, eid);
  k_ve<<<1, 64, 0, stream>>>(We1, a1e, We2, a2e, ve);

  k_proj1<<<NN/PR1, 256, 0, stream>>>(x, W1, a1s, a1d, h1, asrc1, adst1);
  k_agg1<<<NN/4, 256, 0, stream>>>(srcp, ea, meanattr, offsets, deg, eid,
                                   h1, asrc1, adst1, ve, b1, out1);
  k_proj2<<<NN/PR2, 256, 0, stream>>>(out1, W2, a2s, a2d, h2, asrc2, adst2);
  k_agg2<<<NN/4, 256, 0, stream>>>(srcp, ea, meanattr, offsets, deg, eid,
                                   h2, asrc2, adst2, ve, b2, out2);
  k_pool<<<GG, 256, 0, stream>>>(out2, batch, Wl, bl, (float*)d_out);
}

// Round 12
// 627.535 us; speedup vs baseline: 1.6119x; 1.1886x over previous
//
#include <hip/hip_runtime.h>
#include <math.h>

// Problem constants (match reference)
constexpr int NN   = 50000;    // nodes
constexpr int EE   = 1000000;  // edges (before self loops)
constexpr int E2   = EE + NN;  // edges incl self loops
constexpr int HEADS = 4;
constexpr int HID  = 64;
constexpr int GG   = 64;       // graphs
constexpr int NCLS = 2;
constexpr float NEG = 0.2f;

constexpr int PR1 = 8;
constexpr int PB1 = NN / PR1;            // 6250 proj1 blocks
constexpr int EB  = (EE + 255) / 256;    // 3907 edge-count blocks

__device__ __forceinline__ float leaky(float v){ return v > 0.f ? v : NEG * v; }

// -------------------------------------------- fused: proj1 | edge_count | ve
// Independent chains overlapped in one launch (block-role dispatch).
// proj1: h1 = x @ W1, fused a_src/a_dst epilogue (r7-verified structure).
// edge_count: deg histogram only (easum atomics eliminated — mean-attr is
// now computed per-node inside the agg kernels).
__global__ __launch_bounds__(256, 4) void k_fused1(
    const float* __restrict__ x,   const float* __restrict__ W1,
    const float* __restrict__ a1s, const float* __restrict__ a1d,
    float* __restrict__ h1, float* __restrict__ asrc, float* __restrict__ adst,
    const int* __restrict__ dst, int* __restrict__ deg,
    const float* __restrict__ We1, const float* __restrict__ a1e,
    const float* __restrict__ We2, const float* __restrict__ a2e,
    float* __restrict__ ve){
  int bid = blockIdx.x;
  int t = threadIdx.x;
  if (bid < PB1){
    // ---- proj1 role ----
    __shared__ float xs[PR1][64];
    int row0 = bid * PR1;
    for (int i = t; i < PR1*64; i += 256)
      xs[i >> 6][i & 63] = x[row0*64 + i];
    __syncthreads();
    float acc[PR1][4] = {};
    #pragma unroll 2
    for (int k4 = 0; k4 < 16; ++k4){
      float wv0 = W1[(k4*4+0)*256 + t];
      float wv1 = W1[(k4*4+1)*256 + t];
      float wv2 = W1[(k4*4+2)*256 + t];
      float wv3 = W1[(k4*4+3)*256 + t];
      #pragma unroll
      for (int r = 0; r < PR1; ++r){
        float4 xq = *(const float4*)&xs[r][k4*4];  // broadcast
        acc[r][0] = fmaf(xq.x, wv0, acc[r][0]);
        acc[r][1] = fmaf(xq.y, wv1, acc[r][1]);
        acc[r][2] = fmaf(xq.z, wv2, acc[r][2]);
        acc[r][3] = fmaf(xq.w, wv3, acc[r][3]);
      }
    }
    int lane = t & 63, wave = t >> 6;        // wave == head
    float as_w = a1s[t], ad_w = a1d[t];
    #pragma unroll
    for (int r = 0; r < PR1; ++r){
      int row = row0 + r;
      float hv = (acc[r][0] + acc[r][1]) + (acc[r][2] + acc[r][3]);
      h1[row*256 + t] = hv;
      float ps = hv * as_w, pd = hv * ad_w;
      #pragma unroll
      for (int off = 32; off; off >>= 1){ ps += __shfl_xor(ps, off); pd += __shfl_xor(pd, off); }
      if (lane == 0){ asrc[row*4 + wave] = ps; adst[row*4 + wave] = pd; }
    }
  } else if (bid < PB1 + EB){
    // ---- edge-count role (deg only) ----
    int e = (bid - PB1) * 256 + t;
    if (e < EE) atomicAdd(&deg[dst[e]], 1);
  } else {
    // ---- ve role: fold edge-attr projection+attention ----
    if (t < 8){
      int h = t >> 1, d = t & 1;
      float s = 0.f;
      for (int c = 0; c < HID; ++c) s += We1[d*256 + h*64 + c] * a1e[h*64 + c];
      ve[t] = s;                             // ve[h*2+d]
    } else if (t < 10){
      int d = t - 8;
      float s = 0.f;
      for (int c = 0; c < HID; ++c) s += We2[d*64 + c] * a2e[c];
      ve[8 + d] = s;                         // ve2[d]
    }
  }
}

// ---------------------------------------------------------------- CSR build
__global__ __launch_bounds__(1024) void k_scan1(const int* __restrict__ deg,
                                                int* __restrict__ tmp,
                                                int* __restrict__ bsum){
  __shared__ int s[1024];
  int t = threadIdx.x;
  int gid = blockIdx.x * 1024 + t;
  int v = (gid < NN) ? (deg[gid] + 1) : 0;   // +1 for self loop
  s[t] = v;
  __syncthreads();
  for (int off = 1; off < 1024; off <<= 1){
    int u = (t >= off) ? s[t - off] : 0;
    __syncthreads();
    s[t] += u;
    __syncthreads();
  }
  if (gid < NN) tmp[gid] = s[t];             // inclusive scan
  if (t == 1023) bsum[blockIdx.x] = s[1023];
}

__global__ void k_scan2(int* bsum, int nb){
  if (threadIdx.x == 0 && blockIdx.x == 0){
    int run = 0;
    for (int b = 0; b < nb; ++b){ int x = bsum[b]; bsum[b] = run; run += x; }
  }
}

__global__ __launch_bounds__(256) void k_scan3(const int* __restrict__ tmp,
                                               const int* __restrict__ bsum,
                                               const int* __restrict__ deg,
                                               int* __restrict__ offsets,
                                               int* __restrict__ cursor){
  int i = blockIdx.x * 256 + threadIdx.x;
  if (i >= NN) return;
  int excl = tmp[i] - (deg[i] + 1) + bsum[i >> 10];
  offsets[i] = excl;
  cursor[i]  = excl;
}

__global__ __launch_bounds__(256) void k_fill(const int* __restrict__ dst,
                                              int* __restrict__ cursor,
                                              int* __restrict__ eid){
  int t = blockIdx.x * 256 + threadIdx.x;
  if (t < EE){
    int d = dst[t];
    int p = atomicAdd(&cursor[d], 1);
    eid[p] = t;
  } else if (t < E2){
    int i = t - EE;                          // self loop edge id = EE + i
    int p = atomicAdd(&cursor[i], 1);
    eid[p] = EE + i;
  }
}

// ----------------------------------------------- layer 1 softmax + aggregate
// One wave per node. r10: mean-attr computed in-wave (easum atomics gone);
// gather loop reverted to the r7 shfl-broadcast form (A/B: 190 vs 195 µs).
__global__ __launch_bounds__(256) void k_agg1(const int* __restrict__ src,
                                              const float* __restrict__ ea,
                                              const int* __restrict__ offsets,
                                              const int* __restrict__ deg,
                                              const int* __restrict__ eid,
                                              const float* __restrict__ h1,
                                              const float* __restrict__ asrc,
                                              const float* __restrict__ adst,
                                              const float* __restrict__ ve,
                                              const float* __restrict__ b1,
                                              float* __restrict__ out1){
  int node = blockIdx.x * 4 + (threadIdx.x >> 6);
  int lane = threadIdx.x & 63;
  int lo  = offsets[node];
  int cnt = deg[node] + 1;
  int h = lane >> 4;
  float ad0 = adst[node*4+0], ad1 = adst[node*4+1];
  float ad2 = adst[node*4+2], ad3 = adst[node*4+3];
  float v00 = ve[0], v01 = ve[1], v10 = ve[2], v11 = ve[3];
  float v20 = ve[4], v21 = ve[5], v30 = ve[6], v31 = ve[7];

  // Phase A0: load chunk-0 edges; wave-reduce ea sums -> self-loop mean attr
  int  cs = 0; float ce0 = 0.f, ce1 = 0.f;
  bool cself = false, cvalid = lane < cnt;
  float sum0 = 0.f, sum1 = 0.f;
  if (cvalid){
    int e = eid[lo + lane];
    if (e < EE){ cs = src[e]; ce0 = ea[e*2]; ce1 = ea[e*2+1]; sum0 = ce0; sum1 = ce1; }
    else       { cs = node;   cself = true; }
  }
  for (int k = lane + 64; k < cnt; k += 64){ // tail: essentially never (deg~20)
    int e = eid[lo + k];
    if (e < EE){ sum0 += ea[e*2]; sum1 += ea[e*2+1]; }
  }
  #pragma unroll
  for (int off = 32; off; off >>= 1){ sum0 += __shfl_xor(sum0, off); sum1 += __shfl_xor(sum1, off); }
  float dnm = fmaxf((float)(cnt - 1), 1.0f); // fill_value='mean' semantics
  float me0 = sum0 / dnm, me1 = sum1 / dnm;
  if (cself){ ce0 = me0; ce1 = me1; }

  // Phase A: per-head segment max; cache chunk-0 logits+src
  float mx0 = -INFINITY, mx1 = -INFINITY, mx2 = -INFINITY, mx3 = -INFINITY;
  float cal0 = 0.f, cal1 = 0.f, cal2 = 0.f, cal3 = 0.f;
  if (cvalid){
    float s0 = asrc[cs*4+0], s1 = asrc[cs*4+1], s2 = asrc[cs*4+2], s3 = asrc[cs*4+3];
    cal0 = leaky(s0 + ad0 + ce0*v00 + ce1*v01);
    cal1 = leaky(s1 + ad1 + ce0*v10 + ce1*v11);
    cal2 = leaky(s2 + ad2 + ce0*v20 + ce1*v21);
    cal3 = leaky(s3 + ad3 + ce0*v30 + ce1*v31);
    mx0 = cal0; mx1 = cal1; mx2 = cal2; mx3 = cal3;
  }
  for (int k = lane + 64; k < cnt; k += 64){
    int e = eid[lo + k];
    int s; float e0, e1;
    if (e < EE){ s = src[e]; e0 = ea[e*2]; e1 = ea[e*2+1]; }
    else       { s = node;   e0 = me0; e1 = me1; }
    float s0 = asrc[s*4+0], s1 = asrc[s*4+1], s2 = asrc[s*4+2], s3 = asrc[s*4+3];
    mx0 = fmaxf(mx0, leaky(s0 + ad0 + e0*v00 + e1*v01));
    mx1 = fmaxf(mx1, leaky(s1 + ad1 + e0*v10 + e1*v11));
    mx2 = fmaxf(mx2, leaky(s2 + ad2 + e0*v20 + e1*v21));
    mx3 = fmaxf(mx3, leaky(s3 + ad3 + e0*v30 + e1*v31));
  }
  #pragma unroll
  for (int off = 32; off; off >>= 1){
    mx0 = fmaxf(mx0, __shfl_xor(mx0, off));
    mx1 = fmaxf(mx1, __shfl_xor(mx1, off));
    mx2 = fmaxf(mx2, __shfl_xor(mx2, off));
    mx3 = fmaxf(mx3, __shfl_xor(mx3, off));
  }

  // Phases B+C per 64-edge chunk (shfl broadcast — r7-measured form)
  float4 acc = make_float4(0.f, 0.f, 0.f, 0.f);
  float den = 0.f;
  for (int base = 0; base < cnt; base += 64){
    int k = base + lane;
    float w0 = 0.f, w1 = 0.f, w2 = 0.f, w3 = 0.f;
    int sv = 0;
    if (k < cnt){
      float a0, a1, a2, a3; int s;
      if (base == 0){ s = cs; a0 = cal0; a1 = cal1; a2 = cal2; a3 = cal3; }
      else {
        int e = eid[lo + k];
        float e0, e1;
        if (e < EE){ s = src[e]; e0 = ea[e*2]; e1 = ea[e*2+1]; }
        else       { s = node;   e0 = me0; e1 = me1; }
        a0 = leaky(asrc[s*4+0] + ad0 + e0*v00 + e1*v01);
        a1 = leaky(asrc[s*4+1] + ad1 + e0*v10 + e1*v11);
        a2 = leaky(asrc[s*4+2] + ad2 + e0*v20 + e1*v21);
        a3 = leaky(asrc[s*4+3] + ad3 + e0*v30 + e1*v31);
      }
      w0 = __expf(a0 - mx0); w1 = __expf(a1 - mx1);
      w2 = __expf(a2 - mx2); w3 = __expf(a3 - mx3);
      sv = s;
    }
    int m = min(64, cnt - base);
    #pragma unroll 4
    for (int k2 = 0; k2 < m; ++k2){
      int   s  = __shfl(sv, k2);
      float q0 = __shfl(w0, k2);
      float q1 = __shfl(w1, k2);
      float q2 = __shfl(w2, k2);
      float q3 = __shfl(w3, k2);
      float w  = (h == 0) ? q0 : (h == 1) ? q1 : (h == 2) ? q2 : q3;
      float4 v = *(const float4*)&h1[s*256 + lane*4];
      den += w;
      acc.x = fmaf(w, v.x, acc.x);
      acc.y = fmaf(w, v.y, acc.y);
      acc.z = fmaf(w, v.z, acc.z);
      acc.w = fmaf(w, v.w, acc.w);
    }
  }
  float4 bb = *(const float4*)&b1[lane*4];
  float inv = 1.f / den;
  float4 o;
  o.x = fmaxf(fmaf(acc.x, inv, bb.x), 0.f);
  o.y = fmaxf(fmaf(acc.y, inv, bb.y), 0.f);
  o.z = fmaxf(fmaf(acc.z, inv, bb.z), 0.f);
  o.w = fmaxf(fmaf(acc.w, inv, bb.w), 0.f);
  *(float4*)&out1[node*256 + lane*4] = o;
}

// ------------------------------------------------------- layer 2 projection
// (r7-verified: out of top-5.)
constexpr int PR2 = 16;
__global__ __launch_bounds__(256, 4) void k_proj2(const float* __restrict__ out1,
                                                  const float* __restrict__ W2,
                                                  const float* __restrict__ a2s,
                                                  const float* __restrict__ a2d,
                                                  float* __restrict__ h2,
                                                  float* __restrict__ asrc,
                                                  float* __restrict__ adst){
  __shared__ float xs[PR2][256];             // 16 KB
  int t = threadIdx.x;
  int row0 = blockIdx.x * PR2;               // NN % PR2 == 0
  for (int i = t*4; i < PR2*256; i += 1024)
    *(float4*)&xs[i >> 8][i & 255] = *(const float4*)&out1[row0*256 + i];
  __syncthreads();
  int lane = t & 63, wave = t >> 6;
  int rbase = wave * 4;
  float acc[4][4] = {};
  #pragma unroll 2
  for (int k4 = 0; k4 < 64; ++k4){
    float wv0 = W2[(k4*4+0)*64 + lane];
    float wv1 = W2[(k4*4+1)*64 + lane];
    float wv2 = W2[(k4*4+2)*64 + lane];
    float wv3 = W2[(k4*4+3)*64 + lane];
    #pragma unroll
    for (int r = 0; r < 4; ++r){
      float4 xq = *(const float4*)&xs[rbase + r][k4*4];  // broadcast
      acc[r][0] = fmaf(xq.x, wv0, acc[r][0]);
      acc[r][1] = fmaf(xq.y, wv1, acc[r][1]);
      acc[r][2] = fmaf(xq.z, wv2, acc[r][2]);
      acc[r][3] = fmaf(xq.w, wv3, acc[r][3]);
    }
  }
  float aw_s = a2s[lane], aw_d = a2d[lane];
  #pragma unroll
  for (int r = 0; r < 4; ++r){
    int row = row0 + rbase + r;
    float hv = (acc[r][0] + acc[r][1]) + (acc[r][2] + acc[r][3]);
    h2[row*64 + lane] = hv;
    float ps = hv * aw_s, pd = hv * aw_d;
    #pragma unroll
    for (int off = 32; off; off >>= 1){ ps += __shfl_xor(ps, off); pd += __shfl_xor(pd, off); }
    if (lane == 0){ asrc[row] = ps; adst[row] = pd; }
  }
}

// ----------------------------------------------- layer 2 softmax + aggregate
// Keeps r9 LDS staging (plausible agg2 win); mean-attr computed in-wave.
__global__ __launch_bounds__(256) void k_agg2(const int* __restrict__ src,
                                              const float* __restrict__ ea,
                                              const int* __restrict__ offsets,
                                              const int* __restrict__ deg,
                                              const int* __restrict__ eid,
                                              const float* __restrict__ h2,
                                              const float* __restrict__ asrc,
                                              const float* __restrict__ adst,
                                              const float* __restrict__ ve,
                                              const float* __restrict__ b2,
                                              float* __restrict__ out2){
  __shared__ float2 st2[4][64];              // [wave][edge-slot] = {s,w}
  int wave = threadIdx.x >> 6;
  int node = blockIdx.x * 4 + wave;
  int lane = threadIdx.x & 63;
  int lo  = offsets[node];
  int cnt = deg[node] + 1;
  float adI = adst[node];
  float v0 = ve[8], v1 = ve[9];

  // chunk-0 load + in-wave mean attr
  int  cs = 0; float ce0 = 0.f, ce1 = 0.f;
  bool cself = false, cvalid = lane < cnt;
  float sum0 = 0.f, sum1 = 0.f;
  if (cvalid){
    int e = eid[lo + lane];
    if (e < EE){ cs = src[e]; ce0 = ea[e*2]; ce1 = ea[e*2+1]; sum0 = ce0; sum1 = ce1; }
    else       { cs = node;   cself = true; }
  }
  for (int k = lane + 64; k < cnt; k += 64){
    int e = eid[lo + k];
    if (e < EE){ sum0 += ea[e*2]; sum1 += ea[e*2+1]; }
  }
  #pragma unroll
  for (int off = 32; off; off >>= 1){ sum0 += __shfl_xor(sum0, off); sum1 += __shfl_xor(sum1, off); }
  float dnm = fmaxf((float)(cnt - 1), 1.0f);
  float me0 = sum0 / dnm, me1 = sum1 / dnm;
  if (cself){ ce0 = me0; ce1 = me1; }

  float mx = -INFINITY, cal = 0.f;
  if (cvalid){
    cal = leaky(asrc[cs] + adI + ce0*v0 + ce1*v1);
    mx = cal;
  }
  for (int k = lane + 64; k < cnt; k += 64){
    int e = eid[lo + k];
    int s; float e0, e1;
    if (e < EE){ s = src[e]; e0 = ea[e*2]; e1 = ea[e*2+1]; }
    else       { s = node;   e0 = me0; e1 = me1; }
    mx = fmaxf(mx, leaky(asrc[s] + adI + e0*v0 + e1*v1));
  }
  #pragma unroll
  for (int off = 32; off; off >>= 1) mx = fmaxf(mx, __shfl_xor(mx, off));

  float acc = 0.f, den = 0.f;
  for (int base = 0; base < cnt; base += 64){
    int k = base + lane;
    float w = 0.f; int sv = 0;
    if (k < cnt){
      float a; int s;
      if (base == 0){ s = cs; a = cal; }
      else {
        int e = eid[lo + k];
        float e0, e1;
        if (e < EE){ s = src[e]; e0 = ea[e*2]; e1 = ea[e*2+1]; }
        else       { s = node;   e0 = me0; e1 = me1; }
        a = leaky(asrc[s] + adI + e0*v0 + e1*v1);
      }
      w = __expf(a - mx);
      sv = s;
    }
    st2[wave][lane] = make_float2(__int_as_float(sv), w);
    int m = min(64, cnt - base);
    #pragma unroll 4
    for (int k2 = 0; k2 < m; ++k2){
      float2 pr = st2[wave][k2];             // uniform addr: broadcast read
      int   s  = __float_as_int(pr.x);
      float ww = pr.y;
      den += ww;
      acc = fmaf(ww, h2[s*64 + lane], acc);
    }
  }
  out2[node*64 + lane] = fmaxf(acc / den + b2[lane], 0.f);
}

// ------------------------------------------------------- pool + classifier
__global__ __launch_bounds__(256) void k_pool(const float* __restrict__ out2,
                                              const int* __restrict__ batch,
                                              const float* __restrict__ Wl,
                                              const float* __restrict__ bl,
                                              float* __restrict__ out){
  __shared__ float red[4][64];
  __shared__ float sh_mean[64];
  int g = blockIdx.x;
  int t = threadIdx.x, lane = t & 63, wave = t >> 6;
  // batch is sorted: binary search graph range
  int lo = 0, hi = NN;
  while (lo < hi){ int m = (lo + hi) >> 1; if (batch[m] < g) lo = m + 1; else hi = m; }
  int start = lo;
  lo = start; hi = NN;
  while (lo < hi){ int m = (lo + hi) >> 1; if (batch[m] < g + 1) lo = m + 1; else hi = m; }
  int end = lo;
  float acc = 0.f;
  for (int n = start + wave; n < end; n += 4) acc += out2[n*64 + lane];
  red[wave][lane] = acc;
  __syncthreads();
  if (wave == 0){
    float s = red[0][lane] + red[1][lane] + red[2][lane] + red[3][lane];
    sh_mean[lane] = s / fmaxf((float)(end - start), 1.0f);
  }
  __syncthreads();
  if (t < NCLS){
    float o = bl[t];
    for (int c = 0; c < HID; ++c) o = fmaf(sh_mean[c], Wl[c*NCLS + t], o);
    out[g*NCLS + t] = o;
  }
}

// ---------------------------------------------------------------- launcher
extern "C" void kernel_launch(void* const* d_in, const int* in_sizes, int n_in,
                              void* d_out, int out_size, void* d_ws, size_t ws_size,
                              hipStream_t stream){
  const float* x     = (const float*)d_in[0];
  const int*   ei    = (const int*)  d_in[1];
  const float* ea    = (const float*)d_in[2];
  const int*   batch = (const int*)  d_in[3];
  const float* W1    = (const float*)d_in[4];
  const float* a1s   = (const float*)d_in[5];
  const float* a1d   = (const float*)d_in[6];
  const float* We1   = (const float*)d_in[7];
  const float* a1e   = (const float*)d_in[8];
  const float* b1    = (const float*)d_in[9];
  const float* W2    = (const float*)d_in[10];
  const float* a2s   = (const float*)d_in[11];
  const float* a2d   = (const float*)d_in[12];
  const float* We2   = (const float*)d_in[13];
  const float* a2e   = (const float*)d_in[14];
  const float* b2    = (const float*)d_in[15];
  const float* Wl    = (const float*)d_in[16];
  const float* bl    = (const float*)d_in[17];
  const int* srcp = ei;        // edge_index[0]
  const int* dstp = ei + EE;   // edge_index[1]

  char* base = (char*)d_ws;
  size_t off = 0;
  auto alloc = [&](size_t bytes) -> char* {
    char* p = base + off;
    off = (off + bytes + 255) & ~(size_t)255;
    return p;
  };
  // Large persistent regions
  float* h1   = (float*)alloc((size_t)NN*256*4);   // 51.2 MB (layer-1 proj)
  float* out1 = (float*)alloc((size_t)NN*256*4);   // 51.2 MB (layer-1 out)
  // h2/out2 alias the h1 region (h1 dead after k_agg1; strict ordering)
  float* h2   = (float*)h1;                        // NN*64*4 = 12.8 MB
  float* out2 = (float*)(h1 + (size_t)NN*64);      // next 12.8 MB of h1 region
  // Small regions
  float* asrc1    = (float*)alloc((size_t)NN*4*4);
  float* adst1    = (float*)alloc((size_t)NN*4*4);
  float* asrc2    = (float*)alloc((size_t)NN*4);
  float* adst2    = (float*)alloc((size_t)NN*4);
  int*   deg      = (int*)  alloc((size_t)NN*4);
  int*   offsets  = (int*)  alloc((size_t)NN*4);
  int*   cursor   = (int*)  alloc((size_t)NN*4);
  int*   eid      = (int*)  alloc((size_t)E2*4);
  int*   stmp     = (int*)  alloc((size_t)NN*4);
  int*   bsum     = (int*)  alloc(64*4);
  float* ve       = (float*)alloc(16*4);
  if (off > ws_size) return;   // workspace too small: fail loudly (poisoned out)

  hipMemsetAsync(deg, 0, (size_t)NN*4, stream);

  int nb = (NN + 1023) / 1024;
  // fused: proj1 (PB1 blocks) | edge_count (EB blocks) | ve (1 block)
  k_fused1<<<PB1 + EB + 1, 256, 0, stream>>>(x, W1, a1s, a1d, h1, asrc1, adst1,
                                             dstp, deg, We1, a1e, We2, a2e, ve);
  k_scan1<<<nb, 1024, 0, stream>>>(deg, stmp, bsum);
  k_scan2<<<1, 1, 0, stream>>>(bsum, nb);
  k_scan3<<<(NN + 255)/256, 256, 0, stream>>>(stmp, bsum, deg, offsets, cursor);
  k_fill<<<(E2 + 255)/256, 256, 0, stream>>>(dstp, cursor, eid);

  k_agg1<<<NN/4, 256, 0, stream>>>(srcp, ea, offsets, deg, eid,
                                   h1, asrc1, adst1, ve, b1, out1);
  k_proj2<<<NN/PR2, 256, 0, stream>>>(out1, W2, a2s, a2d, h2, asrc2, adst2);
  k_agg2<<<NN/4, 256, 0, stream>>>(srcp, ea, offsets, deg, eid,
                                   h2, asrc2, adst2, ve, b2, out2);
  k_pool<<<GG, 256, 0, stream>>>(out2, batch, Wl, bl, (float*)d_out);
}

// Round 13
// 562.960 us; speedup vs baseline: 1.7968x; 1.1147x over previous
//
#include <hip/hip_runtime.h>
#include <math.h>

// Problem constants (match reference)
constexpr int NN   = 50000;    // nodes
constexpr int EE   = 1000000;  // edges (before self loops)
constexpr int E2   = EE + NN;  // edges incl self loops
constexpr int HEADS = 4;
constexpr int HID  = 64;
constexpr int GG   = 64;       // graphs
constexpr int NCLS = 2;
constexpr float NEG = 0.2f;

constexpr int PR1 = 8;
constexpr int PB1 = NN / PR1;            // 6250 proj1 blocks
constexpr int EB  = (EE + 255) / 256;    // 3907 edge-count blocks

__device__ __forceinline__ float leaky(float v){ return v > 0.f ? v : NEG * v; }

// -------------------------------------------- fused: proj1 | edge_count | ve
// (r12-measured good: total 746 -> 627 with this + easum elimination.)
__global__ __launch_bounds__(256, 4) void k_fused1(
    const float* __restrict__ x,   const float* __restrict__ W1,
    const float* __restrict__ a1s, const float* __restrict__ a1d,
    float* __restrict__ h1, float* __restrict__ asrc, float* __restrict__ adst,
    const int* __restrict__ dst, int* __restrict__ deg,
    const float* __restrict__ We1, const float* __restrict__ a1e,
    const float* __restrict__ We2, const float* __restrict__ a2e,
    float* __restrict__ ve){
  int bid = blockIdx.x;
  int t = threadIdx.x;
  if (bid < PB1){
    // ---- proj1 role ----
    __shared__ float xs[PR1][64];
    int row0 = bid * PR1;
    for (int i = t; i < PR1*64; i += 256)
      xs[i >> 6][i & 63] = x[row0*64 + i];
    __syncthreads();
    float acc[PR1][4] = {};
    #pragma unroll 2
    for (int k4 = 0; k4 < 16; ++k4){
      float wv0 = W1[(k4*4+0)*256 + t];
      float wv1 = W1[(k4*4+1)*256 + t];
      float wv2 = W1[(k4*4+2)*256 + t];
      float wv3 = W1[(k4*4+3)*256 + t];
      #pragma unroll
      for (int r = 0; r < PR1; ++r){
        float4 xq = *(const float4*)&xs[r][k4*4];  // broadcast
        acc[r][0] = fmaf(xq.x, wv0, acc[r][0]);
        acc[r][1] = fmaf(xq.y, wv1, acc[r][1]);
        acc[r][2] = fmaf(xq.z, wv2, acc[r][2]);
        acc[r][3] = fmaf(xq.w, wv3, acc[r][3]);
      }
    }
    int lane = t & 63, wave = t >> 6;        // wave == head
    float as_w = a1s[t], ad_w = a1d[t];
    #pragma unroll
    for (int r = 0; r < PR1; ++r){
      int row = row0 + r;
      float hv = (acc[r][0] + acc[r][1]) + (acc[r][2] + acc[r][3]);
      h1[row*256 + t] = hv;
      float ps = hv * as_w, pd = hv * ad_w;
      #pragma unroll
      for (int off = 32; off; off >>= 1){ ps += __shfl_xor(ps, off); pd += __shfl_xor(pd, off); }
      if (lane == 0){ asrc[row*4 + wave] = ps; adst[row*4 + wave] = pd; }
    }
  } else if (bid < PB1 + EB){
    // ---- edge-count role (deg only) ----
    int e = (bid - PB1) * 256 + t;
    if (e < EE) atomicAdd(&deg[dst[e]], 1);
  } else {
    // ---- ve role: fold edge-attr projection+attention ----
    if (t < 8){
      int h = t >> 1, d = t & 1;
      float s = 0.f;
      for (int c = 0; c < HID; ++c) s += We1[d*256 + h*64 + c] * a1e[h*64 + c];
      ve[t] = s;                             // ve[h*2+d]
    } else if (t < 10){
      int d = t - 8;
      float s = 0.f;
      for (int c = 0; c < HID; ++c) s += We2[d*64 + c] * a2e[c];
      ve[8 + d] = s;                         // ve2[d]
    }
  }
}

// ---------------------------------------------------------------- CSR build
__global__ __launch_bounds__(1024) void k_scan1(const int* __restrict__ deg,
                                                int* __restrict__ tmp,
                                                int* __restrict__ bsum){
  __shared__ int s[1024];
  int t = threadIdx.x;
  int gid = blockIdx.x * 1024 + t;
  int v = (gid < NN) ? (deg[gid] + 1) : 0;   // +1 for self loop
  s[t] = v;
  __syncthreads();
  for (int off = 1; off < 1024; off <<= 1){
    int u = (t >= off) ? s[t - off] : 0;
    __syncthreads();
    s[t] += u;
    __syncthreads();
  }
  if (gid < NN) tmp[gid] = s[t];             // inclusive scan
  if (t == 1023) bsum[blockIdx.x] = s[1023];
}

__global__ void k_scan2(int* bsum, int nb){
  if (threadIdx.x == 0 && blockIdx.x == 0){
    int run = 0;
    for (int b = 0; b < nb; ++b){ int x = bsum[b]; bsum[b] = run; run += x; }
  }
}

__global__ __launch_bounds__(256) void k_scan3(const int* __restrict__ tmp,
                                               const int* __restrict__ bsum,
                                               const int* __restrict__ deg,
                                               int* __restrict__ offsets,
                                               int* __restrict__ cursor){
  int i = blockIdx.x * 256 + threadIdx.x;
  if (i >= NN) return;
  int excl = tmp[i] - (deg[i] + 1) + bsum[i >> 10];
  offsets[i] = excl;
  cursor[i]  = excl;
}

// r13: CSR payload is DIRECT — srcs (sign bit = synthetic self loop) and
// eatt (edge attr) are written in CSR order, so the agg kernels read them
// coalesced instead of random eid->src/ea line fetches (1M x ~128B waste).
__global__ __launch_bounds__(256) void k_fill(const int* __restrict__ dst,
                                              const int* __restrict__ src,
                                              const float* __restrict__ ea,
                                              int* __restrict__ cursor,
                                              int* __restrict__ srcs,
                                              float2* __restrict__ eatt){
  int t = blockIdx.x * 256 + threadIdx.x;
  if (t < EE){
    int d = dst[t];
    int p = atomicAdd(&cursor[d], 1);
    srcs[p] = src[t];
    eatt[p] = make_float2(ea[t*2], ea[t*2+1]);
  } else if (t < E2){
    int i = t - EE;                          // synthetic self loop
    int p = atomicAdd(&cursor[i], 1);
    srcs[p] = i | 0x80000000;                // sign bit: use in-wave mean attr
  }
}

// ----------------------------------------------- layer 1 softmax + aggregate
// One wave per node; coalesced srcs/eatt reads; shfl-broadcast gather (r7).
__global__ __launch_bounds__(256) void k_agg1(const int* __restrict__ srcs,
                                              const float2* __restrict__ eatt,
                                              const int* __restrict__ offsets,
                                              const int* __restrict__ deg,
                                              const float* __restrict__ h1,
                                              const float* __restrict__ asrc,
                                              const float* __restrict__ adst,
                                              const float* __restrict__ ve,
                                              const float* __restrict__ b1,
                                              float* __restrict__ out1){
  int node = blockIdx.x * 4 + (threadIdx.x >> 6);
  int lane = threadIdx.x & 63;
  int lo  = offsets[node];
  int cnt = deg[node] + 1;
  int h = lane >> 4;
  float ad0 = adst[node*4+0], ad1 = adst[node*4+1];
  float ad2 = adst[node*4+2], ad3 = adst[node*4+3];
  float v00 = ve[0], v01 = ve[1], v10 = ve[2], v11 = ve[3];
  float v20 = ve[4], v21 = ve[5], v30 = ve[6], v31 = ve[7];

  // Phase A0: coalesced chunk-0 load; wave-reduce ea sums -> self-loop mean
  int  cs = 0; float ce0 = 0.f, ce1 = 0.f;
  bool cself = false, cvalid = lane < cnt;
  float sum0 = 0.f, sum1 = 0.f;
  if (cvalid){
    int sraw = srcs[lo + lane];
    cself = sraw < 0;
    cs = sraw & 0x7fffffff;
    if (!cself){ float2 ef = eatt[lo + lane]; ce0 = ef.x; ce1 = ef.y; sum0 = ce0; sum1 = ce1; }
  }
  for (int k = lane + 64; k < cnt; k += 64){ // tail: essentially never (deg~20)
    int sraw = srcs[lo + k];
    if (sraw >= 0){ float2 ef = eatt[lo + k]; sum0 += ef.x; sum1 += ef.y; }
  }
  #pragma unroll
  for (int off = 32; off; off >>= 1){ sum0 += __shfl_xor(sum0, off); sum1 += __shfl_xor(sum1, off); }
  float dnm = fmaxf((float)(cnt - 1), 1.0f); // fill_value='mean' semantics
  float me0 = sum0 / dnm, me1 = sum1 / dnm;
  if (cself){ ce0 = me0; ce1 = me1; }

  // Phase A: per-head segment max; cache chunk-0 logits+src
  float mx0 = -INFINITY, mx1 = -INFINITY, mx2 = -INFINITY, mx3 = -INFINITY;
  float cal0 = 0.f, cal1 = 0.f, cal2 = 0.f, cal3 = 0.f;
  if (cvalid){
    float s0 = asrc[cs*4+0], s1 = asrc[cs*4+1], s2 = asrc[cs*4+2], s3 = asrc[cs*4+3];
    cal0 = leaky(s0 + ad0 + ce0*v00 + ce1*v01);
    cal1 = leaky(s1 + ad1 + ce0*v10 + ce1*v11);
    cal2 = leaky(s2 + ad2 + ce0*v20 + ce1*v21);
    cal3 = leaky(s3 + ad3 + ce0*v30 + ce1*v31);
    mx0 = cal0; mx1 = cal1; mx2 = cal2; mx3 = cal3;
  }
  for (int k = lane + 64; k < cnt; k += 64){
    int sraw = srcs[lo + k];
    bool sl = sraw < 0; int s = sraw & 0x7fffffff;
    float2 ef = eatt[lo + k];
    float e0 = sl ? me0 : ef.x, e1 = sl ? me1 : ef.y;
    float s0 = asrc[s*4+0], s1 = asrc[s*4+1], s2 = asrc[s*4+2], s3 = asrc[s*4+3];
    mx0 = fmaxf(mx0, leaky(s0 + ad0 + e0*v00 + e1*v01));
    mx1 = fmaxf(mx1, leaky(s1 + ad1 + e0*v10 + e1*v11));
    mx2 = fmaxf(mx2, leaky(s2 + ad2 + e0*v20 + e1*v21));
    mx3 = fmaxf(mx3, leaky(s3 + ad3 + e0*v30 + e1*v31));
  }
  #pragma unroll
  for (int off = 32; off; off >>= 1){
    mx0 = fmaxf(mx0, __shfl_xor(mx0, off));
    mx1 = fmaxf(mx1, __shfl_xor(mx1, off));
    mx2 = fmaxf(mx2, __shfl_xor(mx2, off));
    mx3 = fmaxf(mx3, __shfl_xor(mx3, off));
  }

  // Phases B+C per 64-edge chunk (shfl broadcast — r7-measured form)
  float4 acc = make_float4(0.f, 0.f, 0.f, 0.f);
  float den = 0.f;
  for (int base = 0; base < cnt; base += 64){
    int k = base + lane;
    float w0 = 0.f, w1 = 0.f, w2 = 0.f, w3 = 0.f;
    int sv = 0;
    if (k < cnt){
      float a0, a1, a2, a3; int s;
      if (base == 0){ s = cs; a0 = cal0; a1 = cal1; a2 = cal2; a3 = cal3; }
      else {
        int sraw = srcs[lo + k];
        bool sl = sraw < 0; s = sraw & 0x7fffffff;
        float2 ef = eatt[lo + k];
        float e0 = sl ? me0 : ef.x, e1 = sl ? me1 : ef.y;
        a0 = leaky(asrc[s*4+0] + ad0 + e0*v00 + e1*v01);
        a1 = leaky(asrc[s*4+1] + ad1 + e0*v10 + e1*v11);
        a2 = leaky(asrc[s*4+2] + ad2 + e0*v20 + e1*v21);
        a3 = leaky(asrc[s*4+3] + ad3 + e0*v30 + e1*v31);
      }
      w0 = __expf(a0 - mx0); w1 = __expf(a1 - mx1);
      w2 = __expf(a2 - mx2); w3 = __expf(a3 - mx3);
      sv = s;
    }
    int m = min(64, cnt - base);
    #pragma unroll 4
    for (int k2 = 0; k2 < m; ++k2){
      int   s  = __shfl(sv, k2);
      float q0 = __shfl(w0, k2);
      float q1 = __shfl(w1, k2);
      float q2 = __shfl(w2, k2);
      float q3 = __shfl(w3, k2);
      float w  = (h == 0) ? q0 : (h == 1) ? q1 : (h == 2) ? q2 : q3;
      float4 v = *(const float4*)&h1[s*256 + lane*4];
      den += w;
      acc.x = fmaf(w, v.x, acc.x);
      acc.y = fmaf(w, v.y, acc.y);
      acc.z = fmaf(w, v.z, acc.z);
      acc.w = fmaf(w, v.w, acc.w);
    }
  }
  float4 bb = *(const float4*)&b1[lane*4];
  float inv = 1.f / den;
  float4 o;
  o.x = fmaxf(fmaf(acc.x, inv, bb.x), 0.f);
  o.y = fmaxf(fmaf(acc.y, inv, bb.y), 0.f);
  o.z = fmaxf(fmaf(acc.z, inv, bb.z), 0.f);
  o.w = fmaxf(fmaf(acc.w, inv, bb.w), 0.f);
  *(float4*)&out1[node*256 + lane*4] = o;
}

// ------------------------------------------------------- layer 2 projection
// (r7-verified: out of top-5.)
constexpr int PR2 = 16;
__global__ __launch_bounds__(256, 4) void k_proj2(const float* __restrict__ out1,
                                                  const float* __restrict__ W2,
                                                  const float* __restrict__ a2s,
                                                  const float* __restrict__ a2d,
                                                  float* __restrict__ h2,
                                                  float* __restrict__ asrc,
                                                  float* __restrict__ adst){
  __shared__ float xs[PR2][256];             // 16 KB
  int t = threadIdx.x;
  int row0 = blockIdx.x * PR2;               // NN % PR2 == 0
  for (int i = t*4; i < PR2*256; i += 1024)
    *(float4*)&xs[i >> 8][i & 255] = *(const float4*)&out1[row0*256 + i];
  __syncthreads();
  int lane = t & 63, wave = t >> 6;
  int rbase = wave * 4;
  float acc[4][4] = {};
  #pragma unroll 2
  for (int k4 = 0; k4 < 64; ++k4){
    float wv0 = W2[(k4*4+0)*64 + lane];
    float wv1 = W2[(k4*4+1)*64 + lane];
    float wv2 = W2[(k4*4+2)*64 + lane];
    float wv3 = W2[(k4*4+3)*64 + lane];
    #pragma unroll
    for (int r = 0; r < 4; ++r){
      float4 xq = *(const float4*)&xs[rbase + r][k4*4];  // broadcast
      acc[r][0] = fmaf(xq.x, wv0, acc[r][0]);
      acc[r][1] = fmaf(xq.y, wv1, acc[r][1]);
      acc[r][2] = fmaf(xq.z, wv2, acc[r][2]);
      acc[r][3] = fmaf(xq.w, wv3, acc[r][3]);
    }
  }
  float aw_s = a2s[lane], aw_d = a2d[lane];
  #pragma unroll
  for (int r = 0; r < 4; ++r){
    int row = row0 + rbase + r;
    float hv = (acc[r][0] + acc[r][1]) + (acc[r][2] + acc[r][3]);
    h2[row*64 + lane] = hv;
    float ps = hv * aw_s, pd = hv * aw_d;
    #pragma unroll
    for (int off = 32; off; off >>= 1){ ps += __shfl_xor(ps, off); pd += __shfl_xor(pd, off); }
    if (lane == 0){ asrc[row] = ps; adst[row] = pd; }
  }
}

// ----------------------------------------------- layer 2 softmax + aggregate
// LDS-staged gather (r12 config); coalesced srcs/eatt; in-wave mean attr.
__global__ __launch_bounds__(256) void k_agg2(const int* __restrict__ srcs,
                                              const float2* __restrict__ eatt,
                                              const int* __restrict__ offsets,
                                              const int* __restrict__ deg,
                                              const float* __restrict__ h2,
                                              const float* __restrict__ asrc,
                                              const float* __restrict__ adst,
                                              const float* __restrict__ ve,
                                              const float* __restrict__ b2,
                                              float* __restrict__ out2){
  __shared__ float2 st2[4][64];              // [wave][edge-slot] = {s,w}
  int wave = threadIdx.x >> 6;
  int node = blockIdx.x * 4 + wave;
  int lane = threadIdx.x & 63;
  int lo  = offsets[node];
  int cnt = deg[node] + 1;
  float adI = adst[node];
  float v0 = ve[8], v1 = ve[9];

  // chunk-0 coalesced load + in-wave mean attr
  int  cs = 0; float ce0 = 0.f, ce1 = 0.f;
  bool cself = false, cvalid = lane < cnt;
  float sum0 = 0.f, sum1 = 0.f;
  if (cvalid){
    int sraw = srcs[lo + lane];
    cself = sraw < 0;
    cs = sraw & 0x7fffffff;
    if (!cself){ float2 ef = eatt[lo + lane]; ce0 = ef.x; ce1 = ef.y; sum0 = ce0; sum1 = ce1; }
  }
  for (int k = lane + 64; k < cnt; k += 64){
    int sraw = srcs[lo + k];
    if (sraw >= 0){ float2 ef = eatt[lo + k]; sum0 += ef.x; sum1 += ef.y; }
  }
  #pragma unroll
  for (int off = 32; off; off >>= 1){ sum0 += __shfl_xor(sum0, off); sum1 += __shfl_xor(sum1, off); }
  float dnm = fmaxf((float)(cnt - 1), 1.0f);
  float me0 = sum0 / dnm, me1 = sum1 / dnm;
  if (cself){ ce0 = me0; ce1 = me1; }

  float mx = -INFINITY, cal = 0.f;
  if (cvalid){
    cal = leaky(asrc[cs] + adI + ce0*v0 + ce1*v1);
    mx = cal;
  }
  for (int k = lane + 64; k < cnt; k += 64){
    int sraw = srcs[lo + k];
    bool sl = sraw < 0; int s = sraw & 0x7fffffff;
    float2 ef = eatt[lo + k];
    float e0 = sl ? me0 : ef.x, e1 = sl ? me1 : ef.y;
    mx = fmaxf(mx, leaky(asrc[s] + adI + e0*v0 + e1*v1));
  }
  #pragma unroll
  for (int off = 32; off; off >>= 1) mx = fmaxf(mx, __shfl_xor(mx, off));

  float acc = 0.f, den = 0.f;
  for (int base = 0; base < cnt; base += 64){
    int k = base + lane;
    float w = 0.f; int sv = 0;
    if (k < cnt){
      float a; int s;
      if (base == 0){ s = cs; a = cal; }
      else {
        int sraw = srcs[lo + k];
        bool sl = sraw < 0; s = sraw & 0x7fffffff;
        float2 ef = eatt[lo + k];
        float e0 = sl ? me0 : ef.x, e1 = sl ? me1 : ef.y;
        a = leaky(asrc[s] + adI + e0*v0 + e1*v1);
      }
      w = __expf(a - mx);
      sv = s;
    }
    st2[wave][lane] = make_float2(__int_as_float(sv), w);
    int m = min(64, cnt - base);
    #pragma unroll 4
    for (int k2 = 0; k2 < m; ++k2){
      float2 pr = st2[wave][k2];             // uniform addr: broadcast read
      int   s  = __float_as_int(pr.x);
      float ww = pr.y;
      den += ww;
      acc = fmaf(ww, h2[s*64 + lane], acc);
    }
  }
  out2[node*64 + lane] = fmaxf(acc / den + b2[lane], 0.f);
}

// ------------------------------------------------------- pool + classifier
__global__ __launch_bounds__(256) void k_pool(const float* __restrict__ out2,
                                              const int* __restrict__ batch,
                                              const float* __restrict__ Wl,
                                              const float* __restrict__ bl,
                                              float* __restrict__ out){
  __shared__ float red[4][64];
  __shared__ float sh_mean[64];
  int g = blockIdx.x;
  int t = threadIdx.x, lane = t & 63, wave = t >> 6;
  // batch is sorted: binary search graph range
  int lo = 0, hi = NN;
  while (lo < hi){ int m = (lo + hi) >> 1; if (batch[m] < g) lo = m + 1; else hi = m; }
  int start = lo;
  lo = start; hi = NN;
  while (lo < hi){ int m = (lo + hi) >> 1; if (batch[m] < g + 1) lo = m + 1; else hi = m; }
  int end = lo;
  float acc = 0.f;
  for (int n = start + wave; n < end; n += 4) acc += out2[n*64 + lane];
  red[wave][lane] = acc;
  __syncthreads();
  if (wave == 0){
    float s = red[0][lane] + red[1][lane] + red[2][lane] + red[3][lane];
    sh_mean[lane] = s / fmaxf((float)(end - start), 1.0f);
  }
  __syncthreads();
  if (t < NCLS){
    float o = bl[t];
    for (int c = 0; c < HID; ++c) o = fmaf(sh_mean[c], Wl[c*NCLS + t], o);
    out[g*NCLS + t] = o;
  }
}

// ---------------------------------------------------------------- launcher
extern "C" void kernel_launch(void* const* d_in, const int* in_sizes, int n_in,
                              void* d_out, int out_size, void* d_ws, size_t ws_size,
                              hipStream_t stream){
  const float* x     = (const float*)d_in[0];
  const int*   ei    = (const int*)  d_in[1];
  const float* ea    = (const float*)d_in[2];
  const int*   batch = (const int*)  d_in[3];
  const float* W1    = (const float*)d_in[4];
  const float* a1s   = (const float*)d_in[5];
  const float* a1d   = (const float*)d_in[6];
  const float* We1   = (const float*)d_in[7];
  const float* a1e   = (const float*)d_in[8];
  const float* b1    = (const float*)d_in[9];
  const float* W2    = (const float*)d_in[10];
  const float* a2s   = (const float*)d_in[11];
  const float* a2d   = (const float*)d_in[12];
  const float* We2   = (const float*)d_in[13];
  const float* a2e   = (const float*)d_in[14];
  const float* b2    = (const float*)d_in[15];
  const float* Wl    = (const float*)d_in[16];
  const float* bl    = (const float*)d_in[17];
  const int* srcp = ei;        // edge_index[0]
  const int* dstp = ei + EE;   // edge_index[1]

  char* base = (char*)d_ws;
  size_t off = 0;
  auto alloc = [&](size_t bytes) -> char* {
    char* p = base + off;
    off = (off + bytes + 255) & ~(size_t)255;
    return p;
  };
  // Large persistent regions
  float* h1   = (float*)alloc((size_t)NN*256*4);   // 51.2 MB (layer-1 proj)
  float* out1 = (float*)alloc((size_t)NN*256*4);   // 51.2 MB (layer-1 out)
  // h2/out2 alias the h1 region (h1 dead after k_agg1; strict ordering)
  float* h2   = (float*)h1;                        // NN*64*4 = 12.8 MB
  float* out2 = (float*)(h1 + (size_t)NN*64);      // next 12.8 MB of h1 region
  // Small regions
  float*  asrc1   = (float*)alloc((size_t)NN*4*4);
  float*  adst1   = (float*)alloc((size_t)NN*4*4);
  float*  asrc2   = (float*)alloc((size_t)NN*4);
  float*  adst2   = (float*)alloc((size_t)NN*4);
  int*    deg     = (int*)  alloc((size_t)NN*4);
  int*    offsets = (int*)  alloc((size_t)NN*4);
  int*    cursor  = (int*)  alloc((size_t)NN*4);
  int*    srcs    = (int*)  alloc((size_t)E2*4);   // CSR: src idx (sign=selfloop)
  float2* eatt    = (float2*)alloc((size_t)E2*8);  // CSR: edge attr
  int*    stmp    = (int*)  alloc((size_t)NN*4);
  int*    bsum    = (int*)  alloc(64*4);
  float*  ve      = (float*)alloc(16*4);
  if (off > ws_size) return;   // workspace too small: fail loudly (poisoned out)

  hipMemsetAsync(deg, 0, (size_t)NN*4, stream);

  int nb = (NN + 1023) / 1024;
  // fused: proj1 (PB1 blocks) | edge_count (EB blocks) | ve (1 block)
  k_fused1<<<PB1 + EB + 1, 256, 0, stream>>>(x, W1, a1s, a1d, h1, asrc1, adst1,
                                             dstp, deg, We1, a1e, We2, a2e, ve);
  k_scan1<<<nb, 1024, 0, stream>>>(deg, stmp, bsum);
  k_scan2<<<1, 1, 0, stream>>>(bsum, nb);
  k_scan3<<<(NN + 255)/256, 256, 0, stream>>>(stmp, bsum, deg, offsets, cursor);
  k_fill<<<(E2 + 255)/256, 256, 0, stream>>>(dstp, srcp, ea, cursor, srcs, eatt);

  k_agg1<<<NN/4, 256, 0, stream>>>(srcs, eatt, offsets, deg,
                                   h1, asrc1, adst1, ve, b1, out1);
  k_proj2<<<NN/PR2, 256, 0, stream>>>(out1, W2, a2s, a2d, h2, asrc2, adst2);
  k_agg2<<<NN/4, 256, 0, stream>>>(srcs, eatt, offsets, deg,
                                   h2, asrc2, adst2, ve, b2, out2);
  k_pool<<<GG, 256, 0, stream>>>(out2, batch, Wl, bl, (float*)d_out);
}